// Round 8
// baseline (844.558 us; speedup 1.0000x reference)
//
#include <hip/hip_runtime.h>
#include <hip/hip_bf16.h>
#include <stdint.h>

// Problem dims
#define Bn 16384
#define Cn 512
#define Dn 512
#define Hn 1024

// a = 1 - 0.95^32 (closed-form Langevin: u32 = -a*e + Z)
#define A32 0.80628851f

typedef __attribute__((ext_vector_type(8))) short bf16x8;   // 8 bf16 (4 VGPRs)
typedef __attribute__((ext_vector_type(4))) float f32x4;    // MFMA accum
typedef __attribute__((ext_vector_type(2))) float f32x2;    // packed fp32 pair

// f32 -> bf16 RTNE (manual; inputs are finite)
__device__ __forceinline__ ushort f2bf(float f) {
  uint32_t u = __float_as_uint(f);
  return (ushort)((u + 0x7fffu + ((u >> 16) & 1u)) >> 16);
}
__device__ __forceinline__ float b2f(ushort u) {
  return __uint_as_float((uint32_t)u << 16);
}

// global -> LDS direct (16B/lane). LDS dest is wave-uniform base + lane*16.
typedef __attribute__((address_space(3))) uint32_t lds_u32_t;
typedef const __attribute__((address_space(1))) uint32_t glb_u32_t;
__device__ __forceinline__ void gload16(const ushort* g, ushort* l) {
  __builtin_amdgcn_global_load_lds((glb_u32_t*)g, (lds_u32_t*)l, 16, 0, 0);
}

// ---------------------------------------------------------------------------
// COMPILE-TIME threefry2x32 key schedule (partitionable JAX, verified round 4)
// ---------------------------------------------------------------------------
constexpr uint32_t crotl(uint32_t v, int s) {
  return (v << s) | (v >> (32 - s));
}
struct TFOut { uint32_t w0, w1; };
constexpr TFOut ctf(uint32_t k0, uint32_t k1, uint32_t x0, uint32_t x1) {
  const uint32_t ks[3] = {k0, k1, k0 ^ k1 ^ 0x1BD11BDAu};
  const int rot[8] = {13, 15, 26, 6, 17, 29, 16, 24};
  uint32_t a = x0 + k0, b = x1 + k1;
  for (int g = 0; g < 5; ++g) {
    for (int i = 0; i < 4; ++i) {
      int r = rot[(g & 1) * 4 + i];
      a += b; b = crotl(b, r); b ^= a;
    }
    a += ks[(g + 1) % 3];
    b += ks[(g + 2) % 3] + (uint32_t)(g + 1);
  }
  return {a, b};
}
struct KeySched { uint32_t s[64]; uint32_t d[64]; };
constexpr KeySched make_keys() {
  KeySched K{};
  TFOut k1 = ctf(0u, 42u, 0u, 0u);  // split(key(42))[0]
  TFOut k2 = ctf(0u, 42u, 0u, 1u);  // split(key(42))[1]
  for (uint32_t t = 0; t < 32; ++t) {
    TFOut ws = ctf(k1.w0, k1.w1, 0u, t);
    K.s[2 * t] = ws.w0; K.s[2 * t + 1] = ws.w1;
    TFOut wd = ctf(k2.w0, k2.w1, 0u, t);
    K.d[2 * t] = wd.w0; K.d[2 * t + 1] = wd.w1;
  }
  return K;
}
// __constant__ so rolled loops can s_load keys (runtime-indexed, uniform).
__constant__ KeySched KS = make_keys();

__device__ __forceinline__ uint32_t rotl32(uint32_t v, int s) {
  return __builtin_rotateleft32(v, (uint32_t)s);
}
__device__ __forceinline__ uint32_t tf_xor(uint32_t K0, uint32_t K1,
                                           uint32_t KX, uint32_t j) {
  uint32_t a = K0, b = K1 + j;
#define TR(r) { a += b; b = rotl32(b, (r)); b ^= a; }
  TR(13) TR(15) TR(26) TR(6)   a += K1; b += KX + 1u;
  TR(17) TR(29) TR(16) TR(24)  a += KX; b += K0 + 2u;
  TR(13) TR(15) TR(26) TR(6)   a += K0; b += K1 + 3u;
  TR(17) TR(29) TR(16) TR(24)  a += K1; b += KX + 4u;
  TR(13) TR(15) TR(26) TR(6)   a += KX; b += K0 + 5u;
#undef TR
  return a ^ b;
}

// Exact (branchy) bits->normal — static-mask path (verified).
__device__ __forceinline__ float bits_to_normal(uint32_t bits) {
  float f = __uint_as_float((bits >> 9) | 0x3f800000u) - 1.0f;
  float x = f * 2.0f - 0x1.fffffep-1f;
  float w = -__logf(1.0f - x * x);
  float p;
  if (w < 5.0f) {
    w -= 2.5f;
    p =            2.81022636e-08f;
    p = fmaf(p, w, 3.43273939e-07f);
    p = fmaf(p, w, -3.5233877e-06f);
    p = fmaf(p, w, -4.39150654e-06f);
    p = fmaf(p, w, 0.00021858087f);
    p = fmaf(p, w, -0.00125372503f);
    p = fmaf(p, w, -0.00417768164f);
    p = fmaf(p, w, 0.246640727f);
    p = fmaf(p, w, 1.50140941f);
  } else {
    w = sqrtf(w) - 3.0f;
    p =            -0.000200214257f;
    p = fmaf(p, w, 0.000100950558f);
    p = fmaf(p, w, 0.00134934322f);
    p = fmaf(p, w, -0.00367342844f);
    p = fmaf(p, w, 0.00573950773f);
    p = fmaf(p, w, -0.0076224613f);
    p = fmaf(p, w, 0.00943887047f);
    p = fmaf(p, w, 1.00167406f);
    p = fmaf(p, w, 2.83297682f);
  }
  return 0x1.6a09e6p+0f * (p * x);
}

// ---------------------------------------------------------------------------
// Z block: 512 elems (2/thread), 2-chain interleave, packed f32x2 tails.
// Rolled (#pragma unroll 4, s_load keys).  Bit-identical per element.
// ---------------------------------------------------------------------------
__device__ __forceinline__ void z_block(ushort* __restrict__ Z, uint32_t zidx) {
  const uint32_t j0 = (zidx * 256u + threadIdx.x) * 2u;
  const uint32_t j1 = j0 + 1u;
  float z0 = 0.0f, z1 = 0.0f;
#pragma unroll 4
  for (int t = 0; t < 32; ++t) {
    const uint32_t K0 = KS.d[2 * t], K1 = KS.d[2 * t + 1];
    const uint32_t KX = K0 ^ K1 ^ 0x1BD11BDAu;
    uint32_t a0 = K0, b0 = K1 + j0;
    uint32_t a1 = K0, b1 = K1 + j1;
#define R2(r)                                                  \
    a0 += b0; a1 += b1;                                        \
    b0 = rotl32(b0, (r)); b1 = rotl32(b1, (r));                \
    b0 ^= a0; b1 ^= a1;
#define I2(p, q) a0 += (p); a1 += (p); b0 += (q); b1 += (q);
    R2(13) R2(15) R2(26) R2(6)  I2(K1, KX + 1u)
    R2(17) R2(29) R2(16) R2(24) I2(KX, K0 + 2u)
    R2(13) R2(15) R2(26) R2(6)  I2(K0, K1 + 3u)
    R2(17) R2(29) R2(16) R2(24) I2(K1, KX + 4u)
    R2(13) R2(15) R2(26) R2(6)  I2(KX, K0 + 5u)
#undef R2
#undef I2
    uint32_t s0 = a0 ^ b0, s1 = a1 ^ b1;
    float f0 = __uint_as_float((s0 >> 9) | 0x3f800000u) - 1.0f;
    float f1 = __uint_as_float((s1 >> 9) | 0x3f800000u) - 1.0f;
    float x0 = f0 * 2.0f - 0x1.fffffep-1f;
    float x1 = f1 * 2.0f - 0x1.fffffep-1f;
    float w0 = fminf(-__logf(fmaf(-x0, x0, 1.0f)), 5.0f) - 2.5f;
    float w1 = fminf(-__logf(fmaf(-x1, x1, 1.0f)), 5.0f) - 2.5f;
    f32x2 X = {x0, x1}, W = {w0, w1};
    f32x2 P = {2.81022636e-08f, 2.81022636e-08f};
    P = __builtin_elementwise_fma(P, W, (f32x2){3.43273939e-07f, 3.43273939e-07f});
    P = __builtin_elementwise_fma(P, W, (f32x2){-3.5233877e-06f, -3.5233877e-06f});
    P = __builtin_elementwise_fma(P, W, (f32x2){-4.39150654e-06f, -4.39150654e-06f});
    P = __builtin_elementwise_fma(P, W, (f32x2){0.00021858087f, 0.00021858087f});
    P = __builtin_elementwise_fma(P, W, (f32x2){-0.00125372503f, -0.00125372503f});
    P = __builtin_elementwise_fma(P, W, (f32x2){-0.00417768164f, -0.00417768164f});
    P = __builtin_elementwise_fma(P, W, (f32x2){0.246640727f, 0.246640727f});
    P = __builtin_elementwise_fma(P, W, (f32x2){1.50140941f, 1.50140941f});
    f32x2 Q = (P * X) * (f32x2){0.14142135f, 0.14142135f};  // 0.1*sqrt(2)
    z0 = fmaf(0.95f, z0, Q.x);
    z1 = fmaf(0.95f, z1, Q.y);
  }
  *(ushort2*)(Z + j0) = make_ushort2(f2bf(z0), f2bf(z1));
}

// ---------------------------------------------------------------------------
// PREP units: cvt_x + 4 LDS-tiled coalesced transposes + smask.
// ---------------------------------------------------------------------------
__device__ __forceinline__ void transpose_tile(
    const float* __restrict__ in, ushort* __restrict__ out,
    int N, int K, int tIdx, float T[32][33]) {
  const int ntn = N / 32;
  const int tk = tIdx / ntn, tn = tIdx % ntn;
  const int tx = threadIdx.x & 31, ty = threadIdx.x >> 5;  // 32 x 8
  const int k0 = tk * 32, n0 = tn * 32;
#pragma unroll
  for (int r = 0; r < 32; r += 8)
    T[ty + r][tx] = in[(size_t)(k0 + ty + r) * N + n0 + tx];
  __syncthreads();
#pragma unroll
  for (int r = 0; r < 32; r += 8)
    out[(size_t)(n0 + ty + r) * K + k0 + tx] = f2bf(T[tx][ty + r]);
}

__device__ __forceinline__ void smask_block(
    const float* __restrict__ vc, const float* __restrict__ e_sp,
    ushort* __restrict__ compsT, int g) {
  uint32_t jj = (uint32_t)g * 256 + threadIdx.x;  // j = d*C + c
  uint32_t c = jj & (Cn - 1), d = jj >> 9;
  uint32_t ridx = c * Dn + d;
  float e = e_sp[ridx];
  float u = 0.0f;
#pragma unroll 4
  for (int t = 0; t < 32; ++t) {
    const uint32_t K0 = KS.s[2 * t], K1 = KS.s[2 * t + 1];
    uint32_t s = tf_xor(K0, K1, K0 ^ K1 ^ 0x1BD11BDAu, ridx);
    float n = bits_to_normal(s);
    u = (u - 0.05f * (u + e)) + 0.1f * n;
  }
  float gt = 1.0f / (1.0f + __expf(u));
  compsT[jj] = f2bf(fabsf(vc[ridx]) * gt);
}

// K1: prep (11264 units) + Z chunk (2816 blocks), mod-5 interleave.
__global__ __launch_bounds__(256, 8) void k_prep_z(
    const float* __restrict__ x, ushort* __restrict__ x_bf,
    const float* __restrict__ W1e, ushort* __restrict__ W1eT,
    const float* __restrict__ W2e, ushort* __restrict__ W2eT,
    const float* __restrict__ W1r, ushort* __restrict__ W1rT,
    const float* __restrict__ W2r, ushort* __restrict__ W2rT,
    const float* __restrict__ vc, const float* __restrict__ e_sp,
    ushort* __restrict__ compsT, ushort* __restrict__ Zd) {
  __shared__ float T[32][33];
  const int pos = blockIdx.x;
  if ((pos % 5) == 4) {                         // 2816 Z blocks: zidx 0..2815
    z_block(Zd, (uint32_t)(pos / 5));
    return;
  }
  const int p = (pos / 5) * 4 + (pos % 5);      // 0..11263 prep units
  if (p < 8192) {
    int i = (p * 256 + threadIdx.x) * 4;
    float4 v = *(const float4*)(x + i);
    *(ushort4*)(x_bf + i) =
        make_ushort4(f2bf(v.x), f2bf(v.y), f2bf(v.z), f2bf(v.w));
  } else if (p < 8704) {
    transpose_tile(W1e, W1eT, Hn, Dn, p - 8192, T);   // [D][H] -> [H][D]
  } else if (p < 9216) {
    transpose_tile(W2e, W2eT, Cn, Hn, p - 8704, T);   // [H][C] -> [C][H]
  } else if (p < 9728) {
    transpose_tile(W1r, W1rT, Hn, Dn, p - 9216, T);
  } else if (p < 10240) {
    transpose_tile(W2r, W2rT, Cn, Hn, p - 9728, T);
  } else {
    smask_block(vc, e_sp, compsT, p - 10240);
  }
}

// ---------------------------------------------------------------------------
// SMALL GEMM core for Z-hosting kernels: 64x64 tile, 4 waves (2x2 of 32x32),
// single-buffered K-loop via global_load_lds, LDS [64][32] linear per
// operand (4 KB each, 8 KB total), XOR-swizzled columns (same verified
// scheme: LDS [row][c] = global [row][c ^ ((row>>1)&3)<<3]; conflicts = 0).
// VGPR budget: acc 2x2xf32x4 (16) + 4 frags (16) + addr (~15) ~= 55, fits
// <= 64 with __launch_bounds__(256,8) -> 8 waves/SIMD -> Z occupancy 2x.
// ---------------------------------------------------------------------------
__device__ __forceinline__ void gemm_core64(
    const ushort* __restrict__ A, const ushort* __restrict__ WT,
    int m0, int n0, int LD, int K,
    ushort* __restrict__ AsL, ushort* __restrict__ BsL,
    f32x4 acc[2][2]) {
  const int t = threadIdx.x;
  const int wave = t >> 6, lane = t & 63;
  const int row = t >> 2;                              // staging row (0..63)
  const int col8 = ((t & 3) << 3) ^ (((t >> 3) & 3) << 3);    // swz'd src col
  const int wr = (wave >> 1) << 5, wc = (wave & 1) << 5;
  const int quad = lane >> 4, l15 = lane & 15;
  const int rc = (quad << 3) ^ (((l15 >> 1) & 3) << 3);       // swz'd read col

  const ushort* ga = A  + (size_t)(m0 + row) * LD + col8;
  const ushort* gb = WT + (size_t)(n0 + row) * LD + col8;
  ushort* la = AsL + wave * 512;           // wave-uniform dests (1 KB/wave)
  ushort* lb = BsL + wave * 512;

  for (int k0 = 0; k0 < K; k0 += 32) {
    gload16(ga + k0, la);
    gload16(gb + k0, lb);
    __syncthreads();                       // drains vmcnt before barrier
    bf16x8 af[2], bfr[2];
#pragma unroll
    for (int i = 0; i < 2; ++i) {
      af[i]  = *(const bf16x8*)&AsL[(wr + i * 16 + l15) * 32 + rc];
      bfr[i] = *(const bf16x8*)&BsL[(wc + i * 16 + l15) * 32 + rc];
    }
#pragma unroll
    for (int i = 0; i < 2; ++i)
#pragma unroll
      for (int j = 0; j < 2; ++j)
        acc[i][j] = __builtin_amdgcn_mfma_f32_16x16x32_bf16(af[i], bfr[j],
                                                            acc[i][j], 0, 0, 0);
    __syncthreads();                       // protect LDS for next stage
  }
}

// bf16 out + bias + relu epilogue (64x64)
__device__ __forceinline__ void gemm_tile_bf64(
    const ushort* __restrict__ A, const ushort* __restrict__ WT,
    const float* __restrict__ bias, ushort* __restrict__ Out,
    int m0, int n0, ushort* AsL, ushort* BsL) {
  const int t = threadIdx.x;
  const int wave = t >> 6, lane = t & 63;
  const int wr = (wave >> 1) << 5, wc = (wave & 1) << 5;
  const int quad = lane >> 4, l15 = lane & 15;
  f32x4 acc[2][2] = {};
  gemm_core64(A, WT, m0, n0, Dn, Dn, AsL, BsL, acc);
#pragma unroll
  for (int i = 0; i < 2; ++i)
#pragma unroll
    for (int j = 0; j < 2; ++j) {
      const int col = n0 + wc + j * 16 + l15;
      const float bv = bias[col];
#pragma unroll
      for (int r = 0; r < 4; ++r) {
        const int row = m0 + wr + i * 16 + quad * 4 + r;
        Out[(size_t)row * Hn + col] = f2bf(fmaxf(acc[i][j][r] + bv, 0.0f));
      }
    }
}

// K2: G1+G3 (8192 64x64 tiles) + Z chunk (4096 blocks), mod-3 interleave.
__global__ __launch_bounds__(256, 8) void k_g13_z(
    const ushort* __restrict__ x_bf,
    const ushort* __restrict__ W1eT, const float* __restrict__ b1e,
    ushort* __restrict__ h,
    const ushort* __restrict__ W1rT, const float* __restrict__ b1r,
    ushort* __restrict__ hr, ushort* __restrict__ Zd) {
  __shared__ ushort AsL[2048];
  __shared__ ushort BsL[2048];
  const int pos = blockIdx.x;                  // 0..12287
  if ((pos % 3) == 2) {                        // 4096 Z: zidx 2816..6911
    z_block(Zd, 2816u + (uint32_t)(pos / 3));
    return;
  }
  const int gg = (pos / 3) * 2 + (pos % 3);    // 0..8191
  const int g = gg >> 1;                       // 0..4095: 256 m x 16 n
  const int m0 = (g >> 4) * 64, n0 = (g & 15) * 64;
  if (gg & 1)
    gemm_tile_bf64(x_bf, W1rT, b1r, hr, m0, n0, AsL, BsL);
  else
    gemm_tile_bf64(x_bf, W1eT, b1e, h, m0, n0, AsL, BsL);
}

// f32 out + bias epilogue (64x64, second-layer GEMMs)
__device__ __forceinline__ void gemm_tile_f32out64(
    const ushort* __restrict__ A, const ushort* __restrict__ WT,
    const float* __restrict__ bias, float* __restrict__ Out,
    int m0, int n0, ushort* AsL, ushort* BsL) {
  const int t = threadIdx.x;
  const int wave = t >> 6, lane = t & 63;
  const int wr = (wave >> 1) << 5, wc = (wave & 1) << 5;
  const int quad = lane >> 4, l15 = lane & 15;
  f32x4 acc[2][2] = {};
  gemm_core64(A, WT, m0, n0, Hn, Hn, AsL, BsL, acc);
#pragma unroll
  for (int i = 0; i < 2; ++i)
#pragma unroll
    for (int j = 0; j < 2; ++j) {
      const int col = n0 + wc + j * 16 + l15;
      const float bv = bias[col];
#pragma unroll
      for (int r = 0; r < 4; ++r) {
        const int row = m0 + wr + i * 16 + quad * 4 + r;
        Out[(size_t)row * Cn + col] = acc[i][j][r] + bv;
      }
    }
}

// K3e: e_raw GEMM (2048 64x64 tiles) + Z chunk (4608 blocks), mod-13.
__global__ __launch_bounds__(256, 8) void k_e_z(
    const ushort* __restrict__ h, const ushort* __restrict__ W2eT,
    const float* __restrict__ b2e, float* __restrict__ e_out,
    ushort* __restrict__ Zd) {
  __shared__ ushort AsL[2048];
  __shared__ ushort BsL[2048];
  const int pos = blockIdx.x;                    // 0..6655 (512*13)
  if ((pos % 13) < 4) {
    const int tg = (pos / 13) * 4 + (pos % 13);  // 0..2047: 256 m x 8 n
    gemm_tile_f32out64(h, W2eT, b2e, e_out, (tg >> 3) * 64, (tg & 7) * 64,
                       AsL, BsL);
  } else {                                       // zidx 6912 + [0,4608)
    z_block(Zd, 6912u + (uint32_t)((pos / 13) * 9 + (pos % 13) - 4));
  }
}

// K3r: conc_raw GEMM (2048 64x64 tiles) + Z chunk (4864 blocks), mod-27.
__global__ __launch_bounds__(256, 8) void k_r_z(
    const ushort* __restrict__ hr, const ushort* __restrict__ W2rT,
    const float* __restrict__ b2r, float* __restrict__ cr_out,
    ushort* __restrict__ Zd) {
  __shared__ ushort AsL[2048];
  __shared__ ushort BsL[2048];
  const int pos = blockIdx.x;                    // 0..6911 (256*27)
  if ((pos % 27) < 8) {
    const int tg = (pos / 27) * 8 + (pos % 27);  // 0..2047: 256 m x 8 n
    gemm_tile_f32out64(hr, W2rT, b2r, cr_out, (tg >> 3) * 64, (tg & 7) * 64,
                       AsL, BsL);
  } else {                                       // zidx 11520 + [0,4864)
    z_block(Zd, 11520u + (uint32_t)((pos / 27) * 19 + (pos % 27) - 8));
  }
}

// ---------------------------------------------------------------------------
// K4: gate apply (elementwise).  conc = bf16(cr * sigmoid(A32*e - z)).
// Identical f32 arithmetic to the former k_dgemm epilogue.
// ---------------------------------------------------------------------------
__global__ __launch_bounds__(256) void k_gate(
    const float* __restrict__ e, const float* __restrict__ cr,
    ushort* __restrict__ Z) {
  const size_t i = ((size_t)blockIdx.x * 256u + threadIdx.x) * 8u;
  uint4 zv = *(const uint4*)(Z + i);
  ushort zs[8];
  *(uint4*)zs = zv;
  float ee[8], cc[8];
  *(float4*)(ee)     = *(const float4*)(e + i);
  *(float4*)(ee + 4) = *(const float4*)(e + i + 4);
  *(float4*)(cc)     = *(const float4*)(cr + i);
  *(float4*)(cc + 4) = *(const float4*)(cr + i + 4);
  ushort os[8];
#pragma unroll
  for (int k = 0; k < 8; ++k) {
    float z = b2f(zs[k]);
    float g = 1.0f / (1.0f + __expf(z - A32 * ee[k]));
    os[k] = f2bf(cc[k] * g);
  }
  *(uint4*)(Z + i) = *(uint4*)os;
}

// ---------------------------------------------------------------------------
// K5: out = conc @ comps — 128x128 double-buffered core (round-7 verified;
// no Z here, so the 80-VGPR allocation costs nothing).
// ---------------------------------------------------------------------------
__device__ __forceinline__ void stage4(
    const ushort* ga0, const ushort* ga1,
    const ushort* gb0, const ushort* gb1,
    int k, ushort* As, ushort* Bs, int wo) {
  gload16(ga0 + k, As + wo);
  gload16(ga1 + k, As + 2048 + wo);
  gload16(gb0 + k, Bs + wo);
  gload16(gb1 + k, Bs + 2048 + wo);
}

__device__ __forceinline__ void mfma16(
    const ushort* Ac, const ushort* Bc,
    int wm, int wn, int l15, int rc, f32x4 acc[4][4]) {
  bf16x8 af[4], bfr[4];
#pragma unroll
  for (int i = 0; i < 4; ++i) {
    af[i]  = *(const bf16x8*)&Ac[(wm + i * 16 + l15) * 32 + rc];
    bfr[i] = *(const bf16x8*)&Bc[(wn + i * 16 + l15) * 32 + rc];
  }
#pragma unroll
  for (int i = 0; i < 4; ++i)
#pragma unroll
    for (int j = 0; j < 4; ++j)
      acc[i][j] = __builtin_amdgcn_mfma_f32_16x16x32_bf16(af[i], bfr[j],
                                                          acc[i][j], 0, 0, 0);
}

__global__ __launch_bounds__(256) void k_gemm_out(
    const ushort* __restrict__ A, const ushort* __restrict__ WT,
    float* __restrict__ Out) {
  __shared__ ushort As0[4096];
  __shared__ ushort Bs0[4096];
  __shared__ ushort As1[4096];
  __shared__ ushort Bs1[4096];
  const int t = threadIdx.x;
  const int m0 = blockIdx.y * 128, n0 = blockIdx.x * 128;
  const int wave = t >> 6, lane = t & 63;
  const int row = t >> 2;
  const int col8 = ((t & 3) << 3) ^ (((t >> 3) & 3) << 3);
  const int wm = (wave >> 1) << 6, wn = (wave & 1) << 6;
  const int quad = lane >> 4, l15 = lane & 15;
  const int rc = (quad << 3) ^ (((l15 >> 1) & 3) << 3);
  const int wo = wave * 512;

  const ushort* ga0 = A  + (size_t)(m0 + row) * Cn + col8;
  const ushort* ga1 = A  + (size_t)(m0 + 64 + row) * Cn + col8;
  const ushort* gb0 = WT + (size_t)(n0 + row) * Cn + col8;
  const ushort* gb1 = WT + (size_t)(n0 + 64 + row) * Cn + col8;

  f32x4 acc[4][4] = {};
  stage4(ga0, ga1, gb0, gb1, 0, As0, Bs0, wo);
  for (int k0 = 0; k0 < Cn; k0 += 64) {
    stage4(ga0, ga1, gb0, gb1, k0 + 32, As1, Bs1, wo);
    asm volatile("s_waitcnt vmcnt(4)" ::: "memory");
    __builtin_amdgcn_sched_barrier(0);
    __builtin_amdgcn_s_barrier();
    mfma16(As0, Bs0, wm, wn, l15, rc, acc);
    __builtin_amdgcn_s_barrier();
    if (k0 + 64 < Cn) {
      stage4(ga0, ga1, gb0, gb1, k0 + 64, As0, Bs0, wo);
      asm volatile("s_waitcnt vmcnt(4)" ::: "memory");
    } else {
      asm volatile("s_waitcnt vmcnt(0)" ::: "memory");
    }
    __builtin_amdgcn_sched_barrier(0);
    __builtin_amdgcn_s_barrier();
    mfma16(As1, Bs1, wm, wn, l15, rc, acc);
    __builtin_amdgcn_s_barrier();
  }
#pragma unroll
  for (int i = 0; i < 4; ++i)
#pragma unroll
    for (int j = 0; j < 4; ++j) {
      const int col = n0 + wn + j * 16 + l15;
#pragma unroll
      for (int r = 0; r < 4; ++r) {
        const int row2 = m0 + wm + i * 16 + quad * 4 + r;
        Out[(size_t)row2 * Dn + col] = acc[i][j][r];
      }
    }
}

// ---------------------------------------------------------------------------
extern "C" void kernel_launch(void* const* d_in, const int* in_sizes, int n_in,
                              void* d_out, int out_size, void* d_ws, size_t ws_size,
                              hipStream_t stream) {
  const float* x    = (const float*)d_in[0];
  const float* vc   = (const float*)d_in[1];
  const float* e_sp = (const float*)d_in[2];
  const float* W1e  = (const float*)d_in[3];
  const float* b1e  = (const float*)d_in[4];
  const float* W2e  = (const float*)d_in[5];
  const float* b2e  = (const float*)d_in[6];
  const float* W1r  = (const float*)d_in[7];
  const float* b1r  = (const float*)d_in[8];
  const float* W2r  = (const float*)d_in[9];
  const float* b2r  = (const float*)d_in[10];
  float* out = (float*)d_out;

  // Workspace (88 MiB high-water, unchanged):
  //   4096    W1eT | +1M W2eT | +2M W1rT | +3M W2rT  (bf16 transposed)
  //   +4M     compsT [D][C] bf16
  //   8M      Zdyn [B][C] bf16 (16 MiB): z -> (gate) -> conc in-place
  //   24M     h  [B][H] bf16 (32 MiB); dead after k_e_z -> cr_f32 [B][C] f32
  //   56M     hr [B][H] bf16 (32 MiB)
  // d_out (32 MiB): x_bf scratch (16 MiB) until k_g13_z; then e_raw f32
  //   (32 MiB) until k_gate; then final out.
  char* ws = (char*)d_ws;
  ushort* W1eT   = (ushort*)(ws + (1u << 12));
  ushort* W2eT   = (ushort*)(ws + (1u << 12) + (1u << 20));
  ushort* W1rT   = (ushort*)(ws + (1u << 12) + (2u << 20));
  ushort* W2rT   = (ushort*)(ws + (1u << 12) + (3u << 20));
  ushort* compsT = (ushort*)(ws + (1u << 12) + (4u << 20));
  ushort* Zdyn   = (ushort*)(ws + (8u << 20));
  ushort* h_bf   = (ushort*)(ws + (24u << 20));
  ushort* hr_bf  = (ushort*)(ws + (56u << 20));
  float*  cr_f32 = (float*)(ws + (24u << 20));   // over dead h_bf
  ushort* x_bf   = (ushort*)d_out;               // scratch until k_e_z
  float*  e_f32  = (float*)d_out;                // after k_g13_z

  // 1. prep (cvt_x, 4 transposes, smask) + Z[0,2816)     — mod-5 interleave
  k_prep_z<<<14080, 256, 0, stream>>>(x, x_bf, W1e, W1eT, W2e, W2eT,
                                      W1r, W1rT, W2r, W2rT, vc, e_sp, compsT,
                                      Zdyn);
  // 2. G1+G3 (h, hr; 8192 64x64 tiles) + Z[2816,6912)    — mod-3 interleave
  k_g13_z<<<12288, 256, 0, stream>>>(x_bf, W1eT, b1e, h_bf, W1rT, b1r, hr_bf,
                                     Zdyn);
  // 3. e_raw = h@W2e+b2e (f32, into d_out) + Z[6912,11520)   — mod-13
  k_e_z<<<6656, 256, 0, stream>>>(h_bf, W2eT, b2e, e_f32, Zdyn);
  // 4. conc_raw = hr@W2r+b2r (f32, over dead h) + Z[11520,16384) — mod-27
  k_r_z<<<6912, 256, 0, stream>>>(hr_bf, W2rT, b2r, cr_f32, Zdyn);
  // 5. gate: conc = bf16(cr * sigmoid(A32*e - z)), in-place over Zdyn
  k_gate<<<4096, 256, 0, stream>>>(e_f32, cr_f32, Zdyn);
  // 6. out = conc @ comps
  k_gemm_out<<<dim3(Dn / 128, Bn / 128), 256, 0, stream>>>(Zdyn, compsT, out);
}

// Round 10
// 817.791 us; speedup vs baseline: 1.0327x; 1.0327x over previous
//
#include <hip/hip_runtime.h>
#include <hip/hip_bf16.h>
#include <stdint.h>

// Problem dims
#define Bn 16384
#define Cn 512
#define Dn 512
#define Hn 1024

// a = 1 - 0.95^32 (closed-form Langevin: u32 = -a*e + Z)
#define A32 0.80628851f

typedef __attribute__((ext_vector_type(8))) short bf16x8;   // 8 bf16 (4 VGPRs)
typedef __attribute__((ext_vector_type(4))) float f32x4;    // MFMA accum
typedef __attribute__((ext_vector_type(2))) float f32x2;    // packed fp32 pair

// f32 -> bf16 RTNE (manual; inputs are finite)
__device__ __forceinline__ ushort f2bf(float f) {
  uint32_t u = __float_as_uint(f);
  return (ushort)((u + 0x7fffu + ((u >> 16) & 1u)) >> 16);
}
__device__ __forceinline__ float b2f(ushort u) {
  return __uint_as_float((uint32_t)u << 16);
}

// global -> LDS direct (16B/lane). LDS dest is wave-uniform base + lane*16.
typedef __attribute__((address_space(3))) uint32_t lds_u32_t;
typedef const __attribute__((address_space(1))) uint32_t glb_u32_t;
__device__ __forceinline__ void gload16(const ushort* g, ushort* l) {
  __builtin_amdgcn_global_load_lds((glb_u32_t*)g, (lds_u32_t*)l, 16, 0, 0);
}

// ---------------------------------------------------------------------------
// COMPILE-TIME threefry2x32 key schedule (partitionable JAX, verified round 4)
// ---------------------------------------------------------------------------
constexpr uint32_t crotl(uint32_t v, int s) {
  return (v << s) | (v >> (32 - s));
}
struct TFOut { uint32_t w0, w1; };
constexpr TFOut ctf(uint32_t k0, uint32_t k1, uint32_t x0, uint32_t x1) {
  const uint32_t ks[3] = {k0, k1, k0 ^ k1 ^ 0x1BD11BDAu};
  const int rot[8] = {13, 15, 26, 6, 17, 29, 16, 24};
  uint32_t a = x0 + k0, b = x1 + k1;
  for (int g = 0; g < 5; ++g) {
    for (int i = 0; i < 4; ++i) {
      int r = rot[(g & 1) * 4 + i];
      a += b; b = crotl(b, r); b ^= a;
    }
    a += ks[(g + 1) % 3];
    b += ks[(g + 2) % 3] + (uint32_t)(g + 1);
  }
  return {a, b};
}
struct KeySched { uint32_t s[64]; uint32_t d[64]; };
constexpr KeySched make_keys() {
  KeySched K{};
  TFOut k1 = ctf(0u, 42u, 0u, 0u);  // split(key(42))[0]
  TFOut k2 = ctf(0u, 42u, 0u, 1u);  // split(key(42))[1]
  for (uint32_t t = 0; t < 32; ++t) {
    TFOut ws = ctf(k1.w0, k1.w1, 0u, t);
    K.s[2 * t] = ws.w0; K.s[2 * t + 1] = ws.w1;
    TFOut wd = ctf(k2.w0, k2.w1, 0u, t);
    K.d[2 * t] = wd.w0; K.d[2 * t + 1] = wd.w1;
  }
  return K;
}
// __constant__ so rolled loops can s_load keys (runtime-indexed, uniform).
__constant__ KeySched KS = make_keys();

__device__ __forceinline__ uint32_t rotl32(uint32_t v, int s) {
  return __builtin_rotateleft32(v, (uint32_t)s);
}
__device__ __forceinline__ uint32_t tf_xor(uint32_t K0, uint32_t K1,
                                           uint32_t KX, uint32_t j) {
  uint32_t a = K0, b = K1 + j;
#define TR(r) { a += b; b = rotl32(b, (r)); b ^= a; }
  TR(13) TR(15) TR(26) TR(6)   a += K1; b += KX + 1u;
  TR(17) TR(29) TR(16) TR(24)  a += KX; b += K0 + 2u;
  TR(13) TR(15) TR(26) TR(6)   a += K0; b += K1 + 3u;
  TR(17) TR(29) TR(16) TR(24)  a += K1; b += KX + 4u;
  TR(13) TR(15) TR(26) TR(6)   a += KX; b += K0 + 5u;
#undef TR
  return a ^ b;
}

// Exact (branchy) bits->normal — static-mask path (verified).
__device__ __forceinline__ float bits_to_normal(uint32_t bits) {
  float f = __uint_as_float((bits >> 9) | 0x3f800000u) - 1.0f;
  float x = f * 2.0f - 0x1.fffffep-1f;
  float w = -__logf(1.0f - x * x);
  float p;
  if (w < 5.0f) {
    w -= 2.5f;
    p =            2.81022636e-08f;
    p = fmaf(p, w, 3.43273939e-07f);
    p = fmaf(p, w, -3.5233877e-06f);
    p = fmaf(p, w, -4.39150654e-06f);
    p = fmaf(p, w, 0.00021858087f);
    p = fmaf(p, w, -0.00125372503f);
    p = fmaf(p, w, -0.00417768164f);
    p = fmaf(p, w, 0.246640727f);
    p = fmaf(p, w, 1.50140941f);
  } else {
    w = sqrtf(w) - 3.0f;
    p =            -0.000200214257f;
    p = fmaf(p, w, 0.000100950558f);
    p = fmaf(p, w, 0.00134934322f);
    p = fmaf(p, w, -0.00367342844f);
    p = fmaf(p, w, 0.00573950773f);
    p = fmaf(p, w, -0.0076224613f);
    p = fmaf(p, w, 0.00943887047f);
    p = fmaf(p, w, 1.00167406f);
    p = fmaf(p, w, 2.83297682f);
  }
  return 0x1.6a09e6p+0f * (p * x);
}

// ---------------------------------------------------------------------------
// One Langevin step for a 2-element chain pair — EXACT ops/order of the
// verified z_block body (bit-identical per element).
// ---------------------------------------------------------------------------
__device__ __forceinline__ void z_step(int t, uint32_t j0, uint32_t j1,
                                       float& z0, float& z1) {
  const uint32_t K0 = KS.d[2 * t], K1 = KS.d[2 * t + 1];
  const uint32_t KX = K0 ^ K1 ^ 0x1BD11BDAu;
  uint32_t a0 = K0, b0 = K1 + j0;
  uint32_t a1 = K0, b1 = K1 + j1;
#define R2(r)                                                  \
  a0 += b0; a1 += b1;                                          \
  b0 = rotl32(b0, (r)); b1 = rotl32(b1, (r));                  \
  b0 ^= a0; b1 ^= a1;
#define I2(p, q) a0 += (p); a1 += (p); b0 += (q); b1 += (q);
  R2(13) R2(15) R2(26) R2(6)  I2(K1, KX + 1u)
  R2(17) R2(29) R2(16) R2(24) I2(KX, K0 + 2u)
  R2(13) R2(15) R2(26) R2(6)  I2(K0, K1 + 3u)
  R2(17) R2(29) R2(16) R2(24) I2(K1, KX + 4u)
  R2(13) R2(15) R2(26) R2(6)  I2(KX, K0 + 5u)
#undef R2
#undef I2
  uint32_t s0 = a0 ^ b0, s1 = a1 ^ b1;
  float f0 = __uint_as_float((s0 >> 9) | 0x3f800000u) - 1.0f;
  float f1 = __uint_as_float((s1 >> 9) | 0x3f800000u) - 1.0f;
  float x0 = f0 * 2.0f - 0x1.fffffep-1f;
  float x1 = f1 * 2.0f - 0x1.fffffep-1f;
  float w0 = fminf(-__logf(fmaf(-x0, x0, 1.0f)), 5.0f) - 2.5f;
  float w1 = fminf(-__logf(fmaf(-x1, x1, 1.0f)), 5.0f) - 2.5f;
  f32x2 X = {x0, x1}, W = {w0, w1};
  f32x2 P = {2.81022636e-08f, 2.81022636e-08f};
  P = __builtin_elementwise_fma(P, W, (f32x2){3.43273939e-07f, 3.43273939e-07f});
  P = __builtin_elementwise_fma(P, W, (f32x2){-3.5233877e-06f, -3.5233877e-06f});
  P = __builtin_elementwise_fma(P, W, (f32x2){-4.39150654e-06f, -4.39150654e-06f});
  P = __builtin_elementwise_fma(P, W, (f32x2){0.00021858087f, 0.00021858087f});
  P = __builtin_elementwise_fma(P, W, (f32x2){-0.00125372503f, -0.00125372503f});
  P = __builtin_elementwise_fma(P, W, (f32x2){-0.00417768164f, -0.00417768164f});
  P = __builtin_elementwise_fma(P, W, (f32x2){0.246640727f, 0.246640727f});
  P = __builtin_elementwise_fma(P, W, (f32x2){1.50140941f, 1.50140941f});
  f32x2 Q = (P * X) * (f32x2){0.14142135f, 0.14142135f};  // 0.1*sqrt(2)
  z0 = fmaf(0.95f, z0, Q.x);
  z1 = fmaf(0.95f, z1, Q.y);
}

// ---------------------------------------------------------------------------
// Z block (256-thread form for k_prep_z, verified): 512 elems, zidx 0..2815.
// ---------------------------------------------------------------------------
__device__ __forceinline__ void z_block(ushort* __restrict__ Z, uint32_t zidx) {
  const uint32_t j0 = (zidx * 256u + threadIdx.x) * 2u;
  const uint32_t j1 = j0 + 1u;
  float z0 = 0.0f, z1 = 0.0f;
#pragma unroll 4
  for (int t = 0; t < 32; ++t) z_step(t, j0, j1, z0, z1);
  *(ushort2*)(Z + j0) = make_ushort2(f2bf(z0), f2bf(z1));
}

// 512-thread pure-Z unit: 1024 elems at base 1441792 + u*1024.
__device__ __forceinline__ void z_unit512(ushort* __restrict__ Z, uint32_t u) {
  const uint32_t j0 = 1441792u + u * 1024u + (uint32_t)threadIdx.x * 2u;
  const uint32_t j1 = j0 + 1u;
  float z0 = 0.0f, z1 = 0.0f;
#pragma unroll 4
  for (int t = 0; t < 32; ++t) z_step(t, j0, j1, z0, z1);
  *(ushort2*)(Z + j0) = make_ushort2(f2bf(z0), f2bf(z1));
}

// ---------------------------------------------------------------------------
// PREP units: cvt_x + 4 LDS-tiled coalesced transposes + smask (verified).
// ---------------------------------------------------------------------------
__device__ __forceinline__ void transpose_tile(
    const float* __restrict__ in, ushort* __restrict__ out,
    int N, int K, int tIdx, float T[32][33]) {
  const int ntn = N / 32;
  const int tk = tIdx / ntn, tn = tIdx % ntn;
  const int tx = threadIdx.x & 31, ty = threadIdx.x >> 5;  // 32 x 8
  const int k0 = tk * 32, n0 = tn * 32;
#pragma unroll
  for (int r = 0; r < 32; r += 8)
    T[ty + r][tx] = in[(size_t)(k0 + ty + r) * N + n0 + tx];
  __syncthreads();
#pragma unroll
  for (int r = 0; r < 32; r += 8)
    out[(size_t)(n0 + ty + r) * K + k0 + tx] = f2bf(T[tx][ty + r]);
}

__device__ __forceinline__ void smask_block(
    const float* __restrict__ vc, const float* __restrict__ e_sp,
    ushort* __restrict__ compsT, int g) {
  uint32_t jj = (uint32_t)g * 256 + threadIdx.x;  // j = d*C + c
  uint32_t c = jj & (Cn - 1), d = jj >> 9;
  uint32_t ridx = c * Dn + d;
  float e = e_sp[ridx];
  float u = 0.0f;
#pragma unroll 4
  for (int t = 0; t < 32; ++t) {
    const uint32_t K0 = KS.s[2 * t], K1 = KS.s[2 * t + 1];
    uint32_t s = tf_xor(K0, K1, K0 ^ K1 ^ 0x1BD11BDAu, ridx);
    float n = bits_to_normal(s);
    u = (u - 0.05f * (u + e)) + 0.1f * n;
  }
  float gt = 1.0f / (1.0f + __expf(u));
  compsT[jj] = f2bf(fabsf(vc[ridx]) * gt);
}

// K1: prep (11264 units) + Z chunk (2816 x 512-elem blocks), mod-5.
__global__ __launch_bounds__(256) void k_prep_z(
    const float* __restrict__ x, ushort* __restrict__ x_bf,
    const float* __restrict__ W1e, ushort* __restrict__ W1eT,
    const float* __restrict__ W2e, ushort* __restrict__ W2eT,
    const float* __restrict__ W1r, ushort* __restrict__ W1rT,
    const float* __restrict__ W2r, ushort* __restrict__ W2rT,
    const float* __restrict__ vc, const float* __restrict__ e_sp,
    ushort* __restrict__ compsT, ushort* __restrict__ Zd) {
  __shared__ float T[32][33];
  const int pos = blockIdx.x;
  if ((pos % 5) == 4) {                         // 2816 Z blocks: zidx 0..2815
    z_block(Zd, (uint32_t)(pos / 5));
    return;
  }
  const int p = (pos / 5) * 4 + (pos % 5);      // 0..11263 prep units
  if (p < 8192) {
    int i = (p * 256 + threadIdx.x) * 4;
    float4 v = *(const float4*)(x + i);
    *(ushort4*)(x_bf + i) =
        make_ushort4(f2bf(v.x), f2bf(v.y), f2bf(v.z), f2bf(v.w));
  } else if (p < 8704) {
    transpose_tile(W1e, W1eT, Hn, Dn, p - 8192, T);   // [D][H] -> [H][D]
  } else if (p < 9216) {
    transpose_tile(W2e, W2eT, Cn, Hn, p - 8704, T);   // [H][C] -> [C][H]
  } else if (p < 9728) {
    transpose_tile(W1r, W1rT, Hn, Dn, p - 9216, T);
  } else if (p < 10240) {
    transpose_tile(W2r, W2rT, Cn, Hn, p - 9728, T);
  } else {
    smask_block(vc, e_sp, compsT, p - 10240);
  }
}

// ---------------------------------------------------------------------------
// FUSED GEMM+Z core: 128x128 tile, 512 threads / 8 waves (each wave 64x32:
// wm=(w>>2)*64, wn=(w&3)*32 -> acc[4][2] = 32 regs/wave).  Single-buffered
// K-loop via global_load_lds; per K-iter each thread stages 16B of A and B
// (identity: LDS byte wave*1024+lane*16 == linear [row=t>>2][col=(t&3)*8]),
// XOR-swizzled columns (verified: LDS [row][c] = global [row][c^((row>>1)&3)
// <<3]; conflicts = 0; write key (lane>>3)&3 == row key == read key
// (l15>>1)&3 — all three derived equal for this thread mapping).
// ZS Langevin steps interleaved per K-iter between the MFMA issue and the
// closing barrier: Z VALU hides under MFMA/load drain.
// ---------------------------------------------------------------------------
template <int KIT, int ZS>
__device__ __forceinline__ void gemm_z_fused(
    const ushort* __restrict__ A, const ushort* __restrict__ WT,
    int m0, int n0, int LD,
    ushort* __restrict__ AsL, ushort* __restrict__ BsL,
    f32x4 acc[4][2], uint32_t j0, uint32_t j1, float& z0, float& z1) {
  const int t = threadIdx.x;
  const int wave = t >> 6, lane = t & 63;
  const int row = t >> 2;                              // staging row 0..127
  const int col8 = ((t & 3) << 3) ^ (((t >> 3) & 3) << 3);    // swz'd src col
  const int wm = (wave >> 2) << 6, wn = (wave & 3) << 5;
  const int l15 = lane & 15, quad = lane >> 4;
  const int rc = (quad << 3) ^ (((l15 >> 1) & 3) << 3);       // swz'd read col

  const ushort* ga = A  + (size_t)(m0 + row) * LD + col8;
  const ushort* gb = WT + (size_t)(n0 + row) * LD + col8;
  ushort* la = AsL + wave * 512;           // wave-uniform dests (1 KB/wave)
  ushort* lb = BsL + wave * 512;

  for (int it = 0; it < KIT; ++it) {
    gload16(ga + it * 32, la);
    gload16(gb + it * 32, lb);
    __syncthreads();                       // drains vmcnt before barrier
    bf16x8 af[4], bfr[2];
#pragma unroll
    for (int i = 0; i < 4; ++i)
      af[i] = *(const bf16x8*)&AsL[(wm + i * 16 + l15) * 32 + rc];
#pragma unroll
    for (int j = 0; j < 2; ++j)
      bfr[j] = *(const bf16x8*)&BsL[(wn + j * 16 + l15) * 32 + rc];
#pragma unroll
    for (int i = 0; i < 4; ++i)
#pragma unroll
      for (int j = 0; j < 2; ++j)
        acc[i][j] = __builtin_amdgcn_mfma_f32_16x16x32_bf16(af[i], bfr[j],
                                                            acc[i][j], 0, 0, 0);
#pragma unroll
    for (int s = 0; s < ZS; ++s)           // Z VALU hides under MFMA drain
      z_step(it * ZS + s, j0, j1, z0, z1);
    __syncthreads();                       // protect LDS for next stage
  }
}

// K2: G1+G3 — 2048 fused tiles (128x128, each hosting 1024 Z elems) +
// 1024 pure-Z units.  Every block is Z-rich -> no resident-mix starvation.
__global__ __launch_bounds__(512, 6) void k_g13_z(
    const ushort* __restrict__ x_bf,
    const ushort* __restrict__ W1eT, const float* __restrict__ b1e,
    ushort* __restrict__ h,
    const ushort* __restrict__ W1rT, const float* __restrict__ b1r,
    ushort* __restrict__ hr, ushort* __restrict__ Zd) {
  __shared__ ushort AsL[4096];
  __shared__ ushort BsL[4096];
  const int pos = blockIdx.x;                  // 0..3071; unit u = pos
  if (pos >= 2048) {                           // pure-Z: u 2048..3071
    z_unit512(Zd, (uint32_t)pos);
    return;
  }
  const uint32_t j0 = 1441792u + (uint32_t)pos * 1024u +
                      (uint32_t)threadIdx.x * 2u;
  const uint32_t j1 = j0 + 1u;
  float z0 = 0.0f, z1 = 0.0f;
  const int tg = pos >> 1;                     // 0..1023: 128 m x 8 n
  const int m0 = (tg >> 3) * 128, n0 = (tg & 7) * 128;
  const ushort* WTp = (pos & 1) ? W1rT : W1eT;
  const float*  bp  = (pos & 1) ? b1r  : b1e;
  ushort*       Op  = (pos & 1) ? hr   : h;
  f32x4 acc[4][2] = {};
  gemm_z_fused<16, 2>(x_bf, WTp, m0, n0, Dn, AsL, BsL, acc, j0, j1, z0, z1);
  *(ushort2*)(Zd + j0) = make_ushort2(f2bf(z0), f2bf(z1));
  const int wave = threadIdx.x >> 6, lane = threadIdx.x & 63;
  const int wm = (wave >> 2) << 6, wn = (wave & 3) << 5;
  const int quad = lane >> 4, l15 = lane & 15;
#pragma unroll
  for (int i = 0; i < 4; ++i)
#pragma unroll
    for (int j = 0; j < 2; ++j) {
      const int col = n0 + wn + j * 16 + l15;
      const float bv = bp[col];
#pragma unroll
      for (int r = 0; r < 4; ++r) {
        const int row = m0 + wm + i * 16 + quad * 4 + r;
        Op[(size_t)row * Hn + col] = f2bf(fmaxf(acc[i][j][r] + bv, 0.0f));
      }
    }
}

// K3e: e_raw — 512 fused tiles + 1344 pure-Z units (u = 3072 + pos).
__global__ __launch_bounds__(512, 6) void k_e_z(
    const ushort* __restrict__ h, const ushort* __restrict__ W2eT,
    const float* __restrict__ b2e, float* __restrict__ e_out,
    ushort* __restrict__ Zd) {
  __shared__ ushort AsL[4096];
  __shared__ ushort BsL[4096];
  const int pos = blockIdx.x;                  // 0..1855
  const uint32_t u = 3072u + (uint32_t)pos;
  if (pos >= 512) {                            // pure-Z: u 3584..4927
    z_unit512(Zd, u);
    return;
  }
  const uint32_t j0 = 1441792u + u * 1024u + (uint32_t)threadIdx.x * 2u;
  const uint32_t j1 = j0 + 1u;
  float z0 = 0.0f, z1 = 0.0f;
  const int m0 = (pos >> 2) * 128, n0 = (pos & 3) * 128;
  f32x4 acc[4][2] = {};
  gemm_z_fused<32, 1>(h, W2eT, m0, n0, Hn, AsL, BsL, acc, j0, j1, z0, z1);
  *(ushort2*)(Zd + j0) = make_ushort2(f2bf(z0), f2bf(z1));
  const int wave = threadIdx.x >> 6, lane = threadIdx.x & 63;
  const int wm = (wave >> 2) << 6, wn = (wave & 3) << 5;
  const int quad = lane >> 4, l15 = lane & 15;
#pragma unroll
  for (int i = 0; i < 4; ++i)
#pragma unroll
    for (int j = 0; j < 2; ++j) {
      const int col = n0 + wn + j * 16 + l15;
      const float bv = b2e[col];
#pragma unroll
      for (int r = 0; r < 4; ++r) {
        const int row = m0 + wm + i * 16 + quad * 4 + r;
        e_out[(size_t)row * Cn + col] = acc[i][j][r] + bv;
      }
    }
}

// K3r: conc_raw — 512 fused tiles + 1344 pure-Z units (u = 4928 + pos).
__global__ __launch_bounds__(512, 6) void k_r_z(
    const ushort* __restrict__ hr, const ushort* __restrict__ W2rT,
    const float* __restrict__ b2r, float* __restrict__ cr_out,
    ushort* __restrict__ Zd) {
  __shared__ ushort AsL[4096];
  __shared__ ushort BsL[4096];
  const int pos = blockIdx.x;                  // 0..1855
  const uint32_t u = 4928u + (uint32_t)pos;
  if (pos >= 512) {                            // pure-Z: u 5440..6783
    z_unit512(Zd, u);
    return;
  }
  const uint32_t j0 = 1441792u + u * 1024u + (uint32_t)threadIdx.x * 2u;
  const uint32_t j1 = j0 + 1u;
  float z0 = 0.0f, z1 = 0.0f;
  const int m0 = (pos >> 2) * 128, n0 = (pos & 3) * 128;
  f32x4 acc[4][2] = {};
  gemm_z_fused<32, 1>(hr, W2rT, m0, n0, Hn, AsL, BsL, acc, j0, j1, z0, z1);
  *(ushort2*)(Zd + j0) = make_ushort2(f2bf(z0), f2bf(z1));
  const int wave = threadIdx.x >> 6, lane = threadIdx.x & 63;
  const int wm = (wave >> 2) << 6, wn = (wave & 3) << 5;
  const int quad = lane >> 4, l15 = lane & 15;
#pragma unroll
  for (int i = 0; i < 4; ++i)
#pragma unroll
    for (int j = 0; j < 2; ++j) {
      const int col = n0 + wn + j * 16 + l15;
      const float bv = b2r[col];
#pragma unroll
      for (int r = 0; r < 4; ++r) {
        const int row = m0 + wm + i * 16 + quad * 4 + r;
        cr_out[(size_t)row * Cn + col] = acc[i][j][r] + bv;
      }
    }
}

// ---------------------------------------------------------------------------
// K4: gate apply (elementwise).  conc = bf16(cr * sigmoid(A32*e - z)).
// Identical f32 arithmetic to the former k_dgemm epilogue.
// ---------------------------------------------------------------------------
__global__ __launch_bounds__(256) void k_gate(
    const float* __restrict__ e, const float* __restrict__ cr,
    ushort* __restrict__ Z) {
  const size_t i = ((size_t)blockIdx.x * 256u + threadIdx.x) * 8u;
  uint4 zv = *(const uint4*)(Z + i);
  ushort zs[8];
  *(uint4*)zs = zv;
  float ee[8], cc[8];
  *(float4*)(ee)     = *(const float4*)(e + i);
  *(float4*)(ee + 4) = *(const float4*)(e + i + 4);
  *(float4*)(cc)     = *(const float4*)(cr + i);
  *(float4*)(cc + 4) = *(const float4*)(cr + i + 4);
  ushort os[8];
#pragma unroll
  for (int k = 0; k < 8; ++k) {
    float z = b2f(zs[k]);
    float g = 1.0f / (1.0f + __expf(z - A32 * ee[k]));
    os[k] = f2bf(cc[k] * g);
  }
  *(uint4*)(Z + i) = *(uint4*)os;
}

// ---------------------------------------------------------------------------
// K5: out = conc @ comps — 128x128 double-buffered core (round-7 verified).
// ---------------------------------------------------------------------------
__device__ __forceinline__ void stage4(
    const ushort* ga0, const ushort* ga1,
    const ushort* gb0, const ushort* gb1,
    int k, ushort* As, ushort* Bs, int wo) {
  gload16(ga0 + k, As + wo);
  gload16(ga1 + k, As + 2048 + wo);
  gload16(gb0 + k, Bs + wo);
  gload16(gb1 + k, Bs + 2048 + wo);
}

__device__ __forceinline__ void mfma16(
    const ushort* Ac, const ushort* Bc,
    int wm, int wn, int l15, int rc, f32x4 acc[4][4]) {
  bf16x8 af[4], bfr[4];
#pragma unroll
  for (int i = 0; i < 4; ++i) {
    af[i]  = *(const bf16x8*)&Ac[(wm + i * 16 + l15) * 32 + rc];
    bfr[i] = *(const bf16x8*)&Bc[(wn + i * 16 + l15) * 32 + rc];
  }
#pragma unroll
  for (int i = 0; i < 4; ++i)
#pragma unroll
    for (int j = 0; j < 4; ++j)
      acc[i][j] = __builtin_amdgcn_mfma_f32_16x16x32_bf16(af[i], bfr[j],
                                                          acc[i][j], 0, 0, 0);
}

__global__ __launch_bounds__(256) void k_gemm_out(
    const ushort* __restrict__ A, const ushort* __restrict__ WT,
    float* __restrict__ Out) {
  __shared__ ushort As0[4096];
  __shared__ ushort Bs0[4096];
  __shared__ ushort As1[4096];
  __shared__ ushort Bs1[4096];
  const int t = threadIdx.x;
  const int m0 = blockIdx.y * 128, n0 = blockIdx.x * 128;
  const int wave = t >> 6, lane = t & 63;
  const int row = t >> 2;
  const int col8 = ((t & 3) << 3) ^ (((t >> 3) & 3) << 3);
  const int wm = (wave >> 1) << 6, wn = (wave & 1) << 6;
  const int quad = lane >> 4, l15 = lane & 15;
  const int rc = (quad << 3) ^ (((l15 >> 1) & 3) << 3);
  const int wo = wave * 512;

  const ushort* ga0 = A  + (size_t)(m0 + row) * Cn + col8;
  const ushort* ga1 = A  + (size_t)(m0 + 64 + row) * Cn + col8;
  const ushort* gb0 = WT + (size_t)(n0 + row) * Cn + col8;
  const ushort* gb1 = WT + (size_t)(n0 + 64 + row) * Cn + col8;

  f32x4 acc[4][4] = {};
  stage4(ga0, ga1, gb0, gb1, 0, As0, Bs0, wo);
  for (int k0 = 0; k0 < Cn; k0 += 64) {
    stage4(ga0, ga1, gb0, gb1, k0 + 32, As1, Bs1, wo);
    asm volatile("s_waitcnt vmcnt(4)" ::: "memory");
    __builtin_amdgcn_sched_barrier(0);
    __builtin_amdgcn_s_barrier();
    mfma16(As0, Bs0, wm, wn, l15, rc, acc);
    __builtin_amdgcn_s_barrier();
    if (k0 + 64 < Cn) {
      stage4(ga0, ga1, gb0, gb1, k0 + 64, As0, Bs0, wo);
      asm volatile("s_waitcnt vmcnt(4)" ::: "memory");
    } else {
      asm volatile("s_waitcnt vmcnt(0)" ::: "memory");
    }
    __builtin_amdgcn_sched_barrier(0);
    __builtin_amdgcn_s_barrier();
    mfma16(As1, Bs1, wm, wn, l15, rc, acc);
    __builtin_amdgcn_s_barrier();
  }
#pragma unroll
  for (int i = 0; i < 4; ++i)
#pragma unroll
    for (int j = 0; j < 4; ++j) {
      const int col = n0 + wn + j * 16 + l15;
#pragma unroll
      for (int r = 0; r < 4; ++r) {
        const int row2 = m0 + wm + i * 16 + quad * 4 + r;
        Out[(size_t)row2 * Dn + col] = acc[i][j][r];
      }
    }
}

// ---------------------------------------------------------------------------
extern "C" void kernel_launch(void* const* d_in, const int* in_sizes, int n_in,
                              void* d_out, int out_size, void* d_ws, size_t ws_size,
                              hipStream_t stream) {
  const float* x    = (const float*)d_in[0];
  const float* vc   = (const float*)d_in[1];
  const float* e_sp = (const float*)d_in[2];
  const float* W1e  = (const float*)d_in[3];
  const float* b1e  = (const float*)d_in[4];
  const float* W2e  = (const float*)d_in[5];
  const float* b2e  = (const float*)d_in[6];
  const float* W1r  = (const float*)d_in[7];
  const float* b1r  = (const float*)d_in[8];
  const float* W2r  = (const float*)d_in[9];
  const float* b2r  = (const float*)d_in[10];
  float* out = (float*)d_out;

  // Workspace (88 MiB high-water, unchanged):
  //   4096    W1eT | +1M W2eT | +2M W1rT | +3M W2rT  (bf16 transposed)
  //   +4M     compsT [D][C] bf16
  //   8M      Zdyn [B][C] bf16 (16 MiB): z -> (gate) -> conc in-place
  //   24M     h  [B][H] bf16 (32 MiB); dead after k_e_z -> cr_f32 [B][C] f32
  //   56M     hr [B][H] bf16 (32 MiB)
  // d_out (32 MiB): x_bf scratch (16 MiB) until k_g13_z; then e_raw f32
  //   (32 MiB) until k_gate; then final out.
  // Z element coverage: prep zidx [0,2816) x 512 elems = [0, 1441792);
  // 512-thread units u in [0,6784) x 1024 elems = [1441792, 8388608).
  char* ws = (char*)d_ws;
  ushort* W1eT   = (ushort*)(ws + (1u << 12));
  ushort* W2eT   = (ushort*)(ws + (1u << 12) + (1u << 20));
  ushort* W1rT   = (ushort*)(ws + (1u << 12) + (2u << 20));
  ushort* W2rT   = (ushort*)(ws + (1u << 12) + (3u << 20));
  ushort* compsT = (ushort*)(ws + (1u << 12) + (4u << 20));
  ushort* Zdyn   = (ushort*)(ws + (8u << 20));
  ushort* h_bf   = (ushort*)(ws + (24u << 20));
  ushort* hr_bf  = (ushort*)(ws + (56u << 20));
  float*  cr_f32 = (float*)(ws + (24u << 20));   // over dead h_bf
  ushort* x_bf   = (ushort*)d_out;               // scratch until k_e_z
  float*  e_f32  = (float*)d_out;                // after k_g13_z

  // 1. prep (cvt_x, 4 transposes, smask) + Z elems [0, 1441792)
  k_prep_z<<<14080, 256, 0, stream>>>(x, x_bf, W1e, W1eT, W2e, W2eT,
                                      W1r, W1rT, W2r, W2rT, vc, e_sp, compsT,
                                      Zdyn);
  // 2. G1+G3: 2048 fused(128x128 + 1024 Z) + 1024 pure-Z units
  k_g13_z<<<3072, 512, 0, stream>>>(x_bf, W1eT, b1e, h_bf, W1rT, b1r, hr_bf,
                                    Zdyn);
  // 3. e_raw: 512 fused + 1344 pure-Z units
  k_e_z<<<1856, 512, 0, stream>>>(h_bf, W2eT, b2e, e_f32, Zdyn);
  // 4. conc_raw: 512 fused + 1344 pure-Z units
  k_r_z<<<1856, 512, 0, stream>>>(hr_bf, W2rT, b2r, cr_f32, Zdyn);
  // 5. gate: conc = bf16(cr * sigmoid(A32*e - z)), in-place over Zdyn
  k_gate<<<4096, 256, 0, stream>>>(e_f32, cr_f32, Zdyn);
  // 6. out = conc @ comps
  k_gemm_out<<<dim3(Dn / 128, Bn / 128), 256, 0, stream>>>(Zdyn, compsT, out);
}

// Round 11
// 771.274 us; speedup vs baseline: 1.0950x; 1.0603x over previous
//
#include <hip/hip_runtime.h>
#include <hip/hip_bf16.h>
#include <stdint.h>

// Problem dims
#define Bn 16384
#define Cn 512
#define Dn 512
#define Hn 1024

// a = 1 - 0.95^32 (closed-form Langevin: u32 = -a*e + Z)
#define A32 0.80628851f

typedef __attribute__((ext_vector_type(8))) short bf16x8;   // 8 bf16 (4 VGPRs)
typedef __attribute__((ext_vector_type(4))) float f32x4;    // MFMA accum
typedef __attribute__((ext_vector_type(2))) float f32x2;    // packed fp32 pair

// f32 -> bf16 RTNE (manual; inputs are finite)
__device__ __forceinline__ ushort f2bf(float f) {
  uint32_t u = __float_as_uint(f);
  return (ushort)((u + 0x7fffu + ((u >> 16) & 1u)) >> 16);
}
__device__ __forceinline__ float b2f(ushort u) {
  return __uint_as_float((uint32_t)u << 16);
}

// global -> LDS direct (16B/lane). LDS dest is wave-uniform base + lane*16.
typedef __attribute__((address_space(3))) uint32_t lds_u32_t;
typedef const __attribute__((address_space(1))) uint32_t glb_u32_t;
__device__ __forceinline__ void gload16(const ushort* g, ushort* l) {
  __builtin_amdgcn_global_load_lds((glb_u32_t*)g, (lds_u32_t*)l, 16, 0, 0);
}

// ---------------------------------------------------------------------------
// COMPILE-TIME threefry2x32 key schedule (partitionable JAX, verified round 4)
// ---------------------------------------------------------------------------
constexpr uint32_t crotl(uint32_t v, int s) {
  return (v << s) | (v >> (32 - s));
}
struct TFOut { uint32_t w0, w1; };
constexpr TFOut ctf(uint32_t k0, uint32_t k1, uint32_t x0, uint32_t x1) {
  const uint32_t ks[3] = {k0, k1, k0 ^ k1 ^ 0x1BD11BDAu};
  const int rot[8] = {13, 15, 26, 6, 17, 29, 16, 24};
  uint32_t a = x0 + k0, b = x1 + k1;
  for (int g = 0; g < 5; ++g) {
    for (int i = 0; i < 4; ++i) {
      int r = rot[(g & 1) * 4 + i];
      a += b; b = crotl(b, r); b ^= a;
    }
    a += ks[(g + 1) % 3];
    b += ks[(g + 2) % 3] + (uint32_t)(g + 1);
  }
  return {a, b};
}
struct KeySched { uint32_t s[64]; uint32_t d[64]; };
constexpr KeySched make_keys() {
  KeySched K{};
  TFOut k1 = ctf(0u, 42u, 0u, 0u);  // split(key(42))[0]
  TFOut k2 = ctf(0u, 42u, 0u, 1u);  // split(key(42))[1]
  for (uint32_t t = 0; t < 32; ++t) {
    TFOut ws = ctf(k1.w0, k1.w1, 0u, t);
    K.s[2 * t] = ws.w0; K.s[2 * t + 1] = ws.w1;
    TFOut wd = ctf(k2.w0, k2.w1, 0u, t);
    K.d[2 * t] = wd.w0; K.d[2 * t + 1] = wd.w1;
  }
  return K;
}
// __constant__ so rolled loops can s_load keys (runtime-indexed, uniform).
__constant__ KeySched KS = make_keys();

__device__ __forceinline__ uint32_t rotl32(uint32_t v, int s) {
  return __builtin_rotateleft32(v, (uint32_t)s);
}
__device__ __forceinline__ uint32_t tf_xor(uint32_t K0, uint32_t K1,
                                           uint32_t KX, uint32_t j) {
  uint32_t a = K0, b = K1 + j;
#define TR(r) { a += b; b = rotl32(b, (r)); b ^= a; }
  TR(13) TR(15) TR(26) TR(6)   a += K1; b += KX + 1u;
  TR(17) TR(29) TR(16) TR(24)  a += KX; b += K0 + 2u;
  TR(13) TR(15) TR(26) TR(6)   a += K0; b += K1 + 3u;
  TR(17) TR(29) TR(16) TR(24)  a += K1; b += KX + 4u;
  TR(13) TR(15) TR(26) TR(6)   a += KX; b += K0 + 5u;
#undef TR
  return a ^ b;
}

// Exact (branchy) bits->normal — static-mask path (verified).
__device__ __forceinline__ float bits_to_normal(uint32_t bits) {
  float f = __uint_as_float((bits >> 9) | 0x3f800000u) - 1.0f;
  float x = f * 2.0f - 0x1.fffffep-1f;
  float w = -__logf(1.0f - x * x);
  float p;
  if (w < 5.0f) {
    w -= 2.5f;
    p =            2.81022636e-08f;
    p = fmaf(p, w, 3.43273939e-07f);
    p = fmaf(p, w, -3.5233877e-06f);
    p = fmaf(p, w, -4.39150654e-06f);
    p = fmaf(p, w, 0.00021858087f);
    p = fmaf(p, w, -0.00125372503f);
    p = fmaf(p, w, -0.00417768164f);
    p = fmaf(p, w, 0.246640727f);
    p = fmaf(p, w, 1.50140941f);
  } else {
    w = sqrtf(w) - 3.0f;
    p =            -0.000200214257f;
    p = fmaf(p, w, 0.000100950558f);
    p = fmaf(p, w, 0.00134934322f);
    p = fmaf(p, w, -0.00367342844f);
    p = fmaf(p, w, 0.00573950773f);
    p = fmaf(p, w, -0.0076224613f);
    p = fmaf(p, w, 0.00943887047f);
    p = fmaf(p, w, 1.00167406f);
    p = fmaf(p, w, 2.83297682f);
  }
  return 0x1.6a09e6p+0f * (p * x);
}

// ---------------------------------------------------------------------------
// One Langevin step for a 2-element chain pair — EXACT ops/order of the
// verified z_block body (bit-identical per element).
// ---------------------------------------------------------------------------
__device__ __forceinline__ void z_step(int t, uint32_t j0, uint32_t j1,
                                       float& z0, float& z1) {
  const uint32_t K0 = KS.d[2 * t], K1 = KS.d[2 * t + 1];
  const uint32_t KX = K0 ^ K1 ^ 0x1BD11BDAu;
  uint32_t a0 = K0, b0 = K1 + j0;
  uint32_t a1 = K0, b1 = K1 + j1;
#define R2(r)                                                  \
  a0 += b0; a1 += b1;                                          \
  b0 = rotl32(b0, (r)); b1 = rotl32(b1, (r));                  \
  b0 ^= a0; b1 ^= a1;
#define I2(p, q) a0 += (p); a1 += (p); b0 += (q); b1 += (q);
  R2(13) R2(15) R2(26) R2(6)  I2(K1, KX + 1u)
  R2(17) R2(29) R2(16) R2(24) I2(KX, K0 + 2u)
  R2(13) R2(15) R2(26) R2(6)  I2(K0, K1 + 3u)
  R2(17) R2(29) R2(16) R2(24) I2(K1, KX + 4u)
  R2(13) R2(15) R2(26) R2(6)  I2(KX, K0 + 5u)
#undef R2
#undef I2
  uint32_t s0 = a0 ^ b0, s1 = a1 ^ b1;
  float f0 = __uint_as_float((s0 >> 9) | 0x3f800000u) - 1.0f;
  float f1 = __uint_as_float((s1 >> 9) | 0x3f800000u) - 1.0f;
  float x0 = f0 * 2.0f - 0x1.fffffep-1f;
  float x1 = f1 * 2.0f - 0x1.fffffep-1f;
  float w0 = fminf(-__logf(fmaf(-x0, x0, 1.0f)), 5.0f) - 2.5f;
  float w1 = fminf(-__logf(fmaf(-x1, x1, 1.0f)), 5.0f) - 2.5f;
  f32x2 X = {x0, x1}, W = {w0, w1};
  f32x2 P = {2.81022636e-08f, 2.81022636e-08f};
  P = __builtin_elementwise_fma(P, W, (f32x2){3.43273939e-07f, 3.43273939e-07f});
  P = __builtin_elementwise_fma(P, W, (f32x2){-3.5233877e-06f, -3.5233877e-06f});
  P = __builtin_elementwise_fma(P, W, (f32x2){-4.39150654e-06f, -4.39150654e-06f});
  P = __builtin_elementwise_fma(P, W, (f32x2){0.00021858087f, 0.00021858087f});
  P = __builtin_elementwise_fma(P, W, (f32x2){-0.00125372503f, -0.00125372503f});
  P = __builtin_elementwise_fma(P, W, (f32x2){-0.00417768164f, -0.00417768164f});
  P = __builtin_elementwise_fma(P, W, (f32x2){0.246640727f, 0.246640727f});
  P = __builtin_elementwise_fma(P, W, (f32x2){1.50140941f, 1.50140941f});
  f32x2 Q = (P * X) * (f32x2){0.14142135f, 0.14142135f};  // 0.1*sqrt(2)
  z0 = fmaf(0.95f, z0, Q.x);
  z1 = fmaf(0.95f, z1, Q.y);
}

// ---------------------------------------------------------------------------
// Z block (256-thread form, verified): 512 elems at zidx*512.
// ---------------------------------------------------------------------------
__device__ __forceinline__ void z_block(ushort* __restrict__ Z, uint32_t zidx) {
  const uint32_t j0 = (zidx * 256u + threadIdx.x) * 2u;
  const uint32_t j1 = j0 + 1u;
  float z0 = 0.0f, z1 = 0.0f;
#pragma unroll 4
  for (int t = 0; t < 32; ++t) z_step(t, j0, j1, z0, z1);
  *(ushort2*)(Z + j0) = make_ushort2(f2bf(z0), f2bf(z1));
}

// ---------------------------------------------------------------------------
// PREP units: cvt_x + 4 LDS-tiled coalesced transposes + smask (verified).
// ---------------------------------------------------------------------------
__device__ __forceinline__ void transpose_tile(
    const float* __restrict__ in, ushort* __restrict__ out,
    int N, int K, int tIdx, float T[32][33]) {
  const int ntn = N / 32;
  const int tk = tIdx / ntn, tn = tIdx % ntn;
  const int tx = threadIdx.x & 31, ty = threadIdx.x >> 5;  // 32 x 8
  const int k0 = tk * 32, n0 = tn * 32;
#pragma unroll
  for (int r = 0; r < 32; r += 8)
    T[ty + r][tx] = in[(size_t)(k0 + ty + r) * N + n0 + tx];
  __syncthreads();
#pragma unroll
  for (int r = 0; r < 32; r += 8)
    out[(size_t)(n0 + ty + r) * K + k0 + tx] = f2bf(T[tx][ty + r]);
}

__device__ __forceinline__ void smask_block(
    const float* __restrict__ vc, const float* __restrict__ e_sp,
    ushort* __restrict__ compsT, int g) {
  uint32_t jj = (uint32_t)g * 256 + threadIdx.x;  // j = d*C + c
  uint32_t c = jj & (Cn - 1), d = jj >> 9;
  uint32_t ridx = c * Dn + d;
  float e = e_sp[ridx];
  float u = 0.0f;
#pragma unroll 4
  for (int t = 0; t < 32; ++t) {
    const uint32_t K0 = KS.s[2 * t], K1 = KS.s[2 * t + 1];
    uint32_t s = tf_xor(K0, K1, K0 ^ K1 ^ 0x1BD11BDAu, ridx);
    float n = bits_to_normal(s);
    u = (u - 0.05f * (u + e)) + 0.1f * n;
  }
  float gt = 1.0f / (1.0f + __expf(u));
  compsT[jj] = f2bf(fabsf(vc[ridx]) * gt);
}

// K1: prep (11264 units) + Z chunk (2816 x 512-elem blocks), mod-5.
__global__ __launch_bounds__(256) void k_prep_z(
    const float* __restrict__ x, ushort* __restrict__ x_bf,
    const float* __restrict__ W1e, ushort* __restrict__ W1eT,
    const float* __restrict__ W2e, ushort* __restrict__ W2eT,
    const float* __restrict__ W1r, ushort* __restrict__ W1rT,
    const float* __restrict__ W2r, ushort* __restrict__ W2rT,
    const float* __restrict__ vc, const float* __restrict__ e_sp,
    ushort* __restrict__ compsT, ushort* __restrict__ Zd) {
  __shared__ float T[32][33];
  const int pos = blockIdx.x;
  if ((pos % 5) == 4) {                         // 2816 Z blocks: zidx 0..2815
    z_block(Zd, (uint32_t)(pos / 5));
    return;
  }
  const int p = (pos / 5) * 4 + (pos % 5);      // 0..11263 prep units
  if (p < 8192) {
    int i = (p * 256 + threadIdx.x) * 4;
    float4 v = *(const float4*)(x + i);
    *(ushort4*)(x_bf + i) =
        make_ushort4(f2bf(v.x), f2bf(v.y), f2bf(v.z), f2bf(v.w));
  } else if (p < 8704) {
    transpose_tile(W1e, W1eT, Hn, Dn, p - 8192, T);   // [D][H] -> [H][D]
  } else if (p < 9216) {
    transpose_tile(W2e, W2eT, Cn, Hn, p - 8704, T);   // [H][C] -> [C][H]
  } else if (p < 9728) {
    transpose_tile(W1r, W1rT, Hn, Dn, p - 9216, T);
  } else if (p < 10240) {
    transpose_tile(W2r, W2rT, Cn, Hn, p - 9728, T);
  } else {
    smask_block(vc, e_sp, compsT, p - 10240);
  }
}

// ---------------------------------------------------------------------------
// FUSED GEMM+Z core (round-10 verified): 128x128 tile, 512 threads / 8 waves
// (each wave 64x32: wm=(w>>2)*64, wn=(w&3)*32 -> acc[4][2] = 32 regs/wave).
// Single-buffered K-loop via global_load_lds; XOR-swizzled columns
// (conflicts = 0; write key (lane>>3)&3 == row key == read key (l15>>1)&3).
// ZS Langevin steps interleaved per K-iter between the MFMA issue and the
// closing barrier: Z VALU hides under MFMA/load drain.
// ---------------------------------------------------------------------------
template <int KIT, int ZS>
__device__ __forceinline__ void gemm_z_fused(
    const ushort* __restrict__ A, const ushort* __restrict__ WT,
    int m0, int n0, int LD,
    ushort* __restrict__ AsL, ushort* __restrict__ BsL,
    f32x4 acc[4][2], uint32_t j0, uint32_t j1, float& z0, float& z1) {
  const int t = threadIdx.x;
  const int wave = t >> 6, lane = t & 63;
  const int row = t >> 2;                              // staging row 0..127
  const int col8 = ((t & 3) << 3) ^ (((t >> 3) & 3) << 3);    // swz'd src col
  const int wm = (wave >> 2) << 6, wn = (wave & 3) << 5;
  const int l15 = lane & 15, quad = lane >> 4;
  const int rc = (quad << 3) ^ (((l15 >> 1) & 3) << 3);       // swz'd read col

  const ushort* ga = A  + (size_t)(m0 + row) * LD + col8;
  const ushort* gb = WT + (size_t)(n0 + row) * LD + col8;
  ushort* la = AsL + wave * 512;           // wave-uniform dests (1 KB/wave)
  ushort* lb = BsL + wave * 512;

  for (int it = 0; it < KIT; ++it) {
    gload16(ga + it * 32, la);
    gload16(gb + it * 32, lb);
    __syncthreads();                       // drains vmcnt before barrier
    bf16x8 af[4], bfr[2];
#pragma unroll
    for (int i = 0; i < 4; ++i)
      af[i] = *(const bf16x8*)&AsL[(wm + i * 16 + l15) * 32 + rc];
#pragma unroll
    for (int j = 0; j < 2; ++j)
      bfr[j] = *(const bf16x8*)&BsL[(wn + j * 16 + l15) * 32 + rc];
#pragma unroll
    for (int i = 0; i < 4; ++i)
#pragma unroll
      for (int j = 0; j < 2; ++j)
        acc[i][j] = __builtin_amdgcn_mfma_f32_16x16x32_bf16(af[i], bfr[j],
                                                            acc[i][j], 0, 0, 0);
#pragma unroll
    for (int s = 0; s < ZS; ++s)           // Z VALU hides under MFMA drain
      z_step(it * ZS + s, j0, j1, z0, z1);
    __syncthreads();                       // protect LDS for next stage
  }
}

// K2: G1+G3 — 2048 fused tiles ONLY (each hosts 1024 Z elems = exactly the
// r7 g13 Z share, elems [1441792, 3538944)).  No pure-Z tail, no starvation:
// every block is Z-rich (r10: VALUBusy 97.7%, VGPR 32, conflicts 0).
__global__ __launch_bounds__(512, 6) void k_g13_z(
    const ushort* __restrict__ x_bf,
    const ushort* __restrict__ W1eT, const float* __restrict__ b1e,
    ushort* __restrict__ h,
    const ushort* __restrict__ W1rT, const float* __restrict__ b1r,
    ushort* __restrict__ hr, ushort* __restrict__ Zd) {
  __shared__ ushort AsL[4096];
  __shared__ ushort BsL[4096];
  const int pos = blockIdx.x;                  // 0..2047, all fused
  const uint32_t j0 = 1441792u + (uint32_t)pos * 1024u +
                      (uint32_t)threadIdx.x * 2u;
  const uint32_t j1 = j0 + 1u;
  float z0 = 0.0f, z1 = 0.0f;
  const int tg = pos >> 1;                     // 0..1023: 128 m x 8 n
  const int m0 = (tg >> 3) * 128, n0 = (tg & 7) * 128;
  const ushort* WTp = (pos & 1) ? W1rT : W1eT;
  const float*  bp  = (pos & 1) ? b1r  : b1e;
  ushort*       Op  = (pos & 1) ? hr   : h;
  f32x4 acc[4][2] = {};
  gemm_z_fused<16, 2>(x_bf, WTp, m0, n0, Dn, AsL, BsL, acc, j0, j1, z0, z1);
  *(ushort2*)(Zd + j0) = make_ushort2(f2bf(z0), f2bf(z1));
  const int wave = threadIdx.x >> 6, lane = threadIdx.x & 63;
  const int wm = (wave >> 2) << 6, wn = (wave & 3) << 5;
  const int quad = lane >> 4, l15 = lane & 15;
#pragma unroll
  for (int i = 0; i < 4; ++i)
#pragma unroll
    for (int j = 0; j < 2; ++j) {
      const int col = n0 + wn + j * 16 + l15;
      const float bv = bp[col];
#pragma unroll
      for (int r = 0; r < 4; ++r) {
        const int row = m0 + wm + i * 16 + quad * 4 + r;
        Op[(size_t)row * Hn + col] = f2bf(fmaxf(acc[i][j][r] + bv, 0.0f));
      }
    }
}

// ---------------------------------------------------------------------------
// 256-thread 128x128 DOUBLE-BUFFERED GEMM core (round-7 verified): counted
// vmcnt + raw s_barrier; sched_barrier(0) after each waitcnt (rule #18).
// XOR-swizzled columns (conflicts = 0).
// ---------------------------------------------------------------------------
__device__ __forceinline__ void stage4(
    const ushort* ga0, const ushort* ga1,
    const ushort* gb0, const ushort* gb1,
    int k, ushort* As, ushort* Bs, int wo) {
  gload16(ga0 + k, As + wo);
  gload16(ga1 + k, As + 2048 + wo);
  gload16(gb0 + k, Bs + wo);
  gload16(gb1 + k, Bs + 2048 + wo);
}

__device__ __forceinline__ void mfma16(
    const ushort* Ac, const ushort* Bc,
    int wm, int wn, int l15, int rc, f32x4 acc[4][4]) {
  bf16x8 af[4], bfr[4];
#pragma unroll
  for (int i = 0; i < 4; ++i) {
    af[i]  = *(const bf16x8*)&Ac[(wm + i * 16 + l15) * 32 + rc];
    bfr[i] = *(const bf16x8*)&Bc[(wn + i * 16 + l15) * 32 + rc];
  }
#pragma unroll
  for (int i = 0; i < 4; ++i)
#pragma unroll
    for (int j = 0; j < 4; ++j)
      acc[i][j] = __builtin_amdgcn_mfma_f32_16x16x32_bf16(af[i], bfr[j],
                                                          acc[i][j], 0, 0, 0);
}

__device__ __forceinline__ void gemm_core(
    const ushort* __restrict__ A, const ushort* __restrict__ WT,
    int m0, int n0, int LD, int K,
    ushort* __restrict__ As0, ushort* __restrict__ Bs0,
    ushort* __restrict__ As1, ushort* __restrict__ Bs1,
    f32x4 acc[4][4]) {
  const int t = threadIdx.x;
  const int wave = t >> 6, lane = t & 63;
  const int row = t >> 2;                              // staging row (0..63)
  const int col8 = ((t & 3) << 3) ^ (((t >> 3) & 3) << 3);    // swz'd src col
  const int wm = (wave >> 1) << 6, wn = (wave & 1) << 6;
  const int quad = lane >> 4, l15 = lane & 15;
  const int rc = (quad << 3) ^ (((l15 >> 1) & 3) << 3);       // swz'd read col
  const int wo = wave * 512;

  const ushort* ga0 = A  + (size_t)(m0 + row) * LD + col8;
  const ushort* ga1 = A  + (size_t)(m0 + 64 + row) * LD + col8;
  const ushort* gb0 = WT + (size_t)(n0 + row) * LD + col8;
  const ushort* gb1 = WT + (size_t)(n0 + 64 + row) * LD + col8;

  stage4(ga0, ga1, gb0, gb1, 0, As0, Bs0, wo);        // prologue: k=0 -> buf0

  for (int k0 = 0; k0 < K; k0 += 64) {                // K % 64 == 0 always
    stage4(ga0, ga1, gb0, gb1, k0 + 32, As1, Bs1, wo);
    asm volatile("s_waitcnt vmcnt(4)" ::: "memory");  // buf0's 4 loads done
    __builtin_amdgcn_sched_barrier(0);
    __builtin_amdgcn_s_barrier();
    mfma16(As0, Bs0, wm, wn, l15, rc, acc);
    __builtin_amdgcn_s_barrier();
    if (k0 + 64 < K) {
      stage4(ga0, ga1, gb0, gb1, k0 + 64, As0, Bs0, wo);
      asm volatile("s_waitcnt vmcnt(4)" ::: "memory");
    } else {
      asm volatile("s_waitcnt vmcnt(0)" ::: "memory");
    }
    __builtin_amdgcn_sched_barrier(0);
    __builtin_amdgcn_s_barrier();
    mfma16(As1, Bs1, wm, wn, l15, rc, acc);
    __builtin_amdgcn_s_barrier();
  }
}

// f32 out + bias epilogue (second-layer GEMMs)
__device__ __forceinline__ void gemm_tile_f32out(
    const ushort* __restrict__ A, const ushort* __restrict__ WT,
    const float* __restrict__ bias, float* __restrict__ Out,
    int m0, int n0, ushort* As0, ushort* Bs0, ushort* As1, ushort* Bs1) {
  const int t = threadIdx.x;
  const int wave = t >> 6, lane = t & 63;
  const int wm = (wave >> 1) << 6, wn = (wave & 1) << 6;
  const int quad = lane >> 4, l15 = lane & 15;
  f32x4 acc[4][4] = {};
  gemm_core(A, WT, m0, n0, Hn, Hn, As0, Bs0, As1, Bs1, acc);
#pragma unroll
  for (int i = 0; i < 4; ++i)
#pragma unroll
    for (int j = 0; j < 4; ++j) {
      const int col = n0 + wn + j * 16 + l15;
      const float bv = bias[col];
#pragma unroll
      for (int r = 0; r < 4; ++r) {
        const int row = m0 + wm + i * 16 + quad * 4 + r;
        Out[(size_t)row * Cn + col] = acc[i][j][r] + bv;
      }
    }
}

// K3e: e_raw GEMM (512 tiles) + Z chunk (4608 blocks), mod-10 (r7 verified).
__global__ __launch_bounds__(256) void k_e_z(
    const ushort* __restrict__ h, const ushort* __restrict__ W2eT,
    const float* __restrict__ b2e, float* __restrict__ e_out,
    ushort* __restrict__ Zd) {
  __shared__ ushort As0[4096];
  __shared__ ushort Bs0[4096];
  __shared__ ushort As1[4096];
  __shared__ ushort Bs1[4096];
  const int pos = blockIdx.x;                    // 0..5119
  if ((pos % 10) == 0) {
    const int tg = pos / 10;                     // 0..511
    gemm_tile_f32out(h, W2eT, b2e, e_out, (tg >> 2) * 128, (tg & 3) * 128,
                     As0, Bs0, As1, Bs1);
  } else {                                       // zidx 6912..11519
    z_block(Zd, 6912u + (uint32_t)(pos / 10) * 9u + (uint32_t)(pos % 10) - 1u);
  }
}

// K3r: conc_raw GEMM (512 tiles) + Z chunk (4864 blocks), mod-10 (r7).
__global__ __launch_bounds__(256) void k_r_z(
    const ushort* __restrict__ hr, const ushort* __restrict__ W2rT,
    const float* __restrict__ b2r, float* __restrict__ cr_out,
    ushort* __restrict__ Zd) {
  __shared__ ushort As0[4096];
  __shared__ ushort Bs0[4096];
  __shared__ ushort As1[4096];
  __shared__ ushort Bs1[4096];
  const int pos = blockIdx.x;                    // 0..5375
  if (pos >= 5120) {                             // zidx 16128..16383
    z_block(Zd, 16128u + (uint32_t)(pos - 5120));
    return;
  }
  if ((pos % 10) == 0) {
    const int tg = pos / 10;                     // 0..511
    gemm_tile_f32out(hr, W2rT, b2r, cr_out, (tg >> 2) * 128, (tg & 3) * 128,
                     As0, Bs0, As1, Bs1);
  } else {                                       // zidx 11520..16127
    z_block(Zd, 11520u + (uint32_t)(pos / 10) * 9u + (uint32_t)(pos % 10) - 1u);
  }
}

// ---------------------------------------------------------------------------
// K4: gate apply (elementwise).  conc = bf16(cr * sigmoid(A32*e - z)).
// Identical f32 arithmetic to the former k_dgemm epilogue.
// ---------------------------------------------------------------------------
__global__ __launch_bounds__(256) void k_gate(
    const float* __restrict__ e, const float* __restrict__ cr,
    ushort* __restrict__ Z) {
  const size_t i = ((size_t)blockIdx.x * 256u + threadIdx.x) * 8u;
  uint4 zv = *(const uint4*)(Z + i);
  ushort zs[8];
  *(uint4*)zs = zv;
  float ee[8], cc[8];
  *(float4*)(ee)     = *(const float4*)(e + i);
  *(float4*)(ee + 4) = *(const float4*)(e + i + 4);
  *(float4*)(cc)     = *(const float4*)(cr + i);
  *(float4*)(cc + 4) = *(const float4*)(cr + i + 4);
  ushort os[8];
#pragma unroll
  for (int k = 0; k < 8; ++k) {
    float z = b2f(zs[k]);
    float g = 1.0f / (1.0f + __expf(z - A32 * ee[k]));
    os[k] = f2bf(cc[k] * g);
  }
  *(uint4*)(Z + i) = *(uint4*)os;
}

// ---------------------------------------------------------------------------
// K5: out = conc @ comps — 128x128 double-buffered core (round-7 verified).
// ---------------------------------------------------------------------------
__global__ __launch_bounds__(256) void k_gemm_out(
    const ushort* __restrict__ A, const ushort* __restrict__ WT,
    float* __restrict__ Out) {
  __shared__ ushort As0[4096];
  __shared__ ushort Bs0[4096];
  __shared__ ushort As1[4096];
  __shared__ ushort Bs1[4096];
  const int t = threadIdx.x;
  const int m0 = blockIdx.y * 128, n0 = blockIdx.x * 128;
  const int wave = t >> 6, lane = t & 63;
  const int wm = (wave >> 1) << 6, wn = (wave & 1) << 6;
  const int quad = lane >> 4, l15 = lane & 15;
  f32x4 acc[4][4] = {};
  gemm_core(A, WT, m0, n0, Cn, Cn, As0, Bs0, As1, Bs1, acc);
#pragma unroll
  for (int i = 0; i < 4; ++i)
#pragma unroll
    for (int j = 0; j < 4; ++j) {
      const int col = n0 + wn + j * 16 + l15;
#pragma unroll
      for (int r = 0; r < 4; ++r) {
        const int row2 = m0 + wm + i * 16 + quad * 4 + r;
        Out[(size_t)row2 * Dn + col] = acc[i][j][r];
      }
    }
}

// ---------------------------------------------------------------------------
extern "C" void kernel_launch(void* const* d_in, const int* in_sizes, int n_in,
                              void* d_out, int out_size, void* d_ws, size_t ws_size,
                              hipStream_t stream) {
  const float* x    = (const float*)d_in[0];
  const float* vc   = (const float*)d_in[1];
  const float* e_sp = (const float*)d_in[2];
  const float* W1e  = (const float*)d_in[3];
  const float* b1e  = (const float*)d_in[4];
  const float* W2e  = (const float*)d_in[5];
  const float* b2e  = (const float*)d_in[6];
  const float* W1r  = (const float*)d_in[7];
  const float* b1r  = (const float*)d_in[8];
  const float* W2r  = (const float*)d_in[9];
  const float* b2r  = (const float*)d_in[10];
  float* out = (float*)d_out;

  // Workspace (88 MiB high-water, unchanged):
  //   4096    W1eT | +1M W2eT | +2M W1rT | +3M W2rT  (bf16 transposed)
  //   +4M     compsT [D][C] bf16
  //   8M      Zdyn [B][C] bf16 (16 MiB): z -> (gate) -> conc in-place
  //   24M     h  [B][H] bf16 (32 MiB); dead after k_e_z -> cr_f32 [B][C] f32
  //   56M     hr [B][H] bf16 (32 MiB)
  // d_out (32 MiB): x_bf scratch (16 MiB) until k_g13_z; then e_raw f32
  //   (32 MiB) until k_gate; then final out.
  // Z element coverage: prep zidx [0,2816)x512 = [0, 1441792); g13 fused
  //   2048x1024 = [1441792, 3538944) (== zidx 2816..6911); e zidx
  //   6912..11519; r zidx 11520..16383.  Complete, disjoint.
  char* ws = (char*)d_ws;
  ushort* W1eT   = (ushort*)(ws + (1u << 12));
  ushort* W2eT   = (ushort*)(ws + (1u << 12) + (1u << 20));
  ushort* W1rT   = (ushort*)(ws + (1u << 12) + (2u << 20));
  ushort* W2rT   = (ushort*)(ws + (1u << 12) + (3u << 20));
  ushort* compsT = (ushort*)(ws + (1u << 12) + (4u << 20));
  ushort* Zdyn   = (ushort*)(ws + (8u << 20));
  ushort* h_bf   = (ushort*)(ws + (24u << 20));
  ushort* hr_bf  = (ushort*)(ws + (56u << 20));
  float*  cr_f32 = (float*)(ws + (24u << 20));   // over dead h_bf
  ushort* x_bf   = (ushort*)d_out;               // scratch until k_e_z
  float*  e_f32  = (float*)d_out;                // after k_g13_z

  // 1. prep (cvt_x, 4 transposes, smask) + Z elems [0, 1441792)
  k_prep_z<<<14080, 256, 0, stream>>>(x, x_bf, W1e, W1eT, W2e, W2eT,
                                      W1r, W1rT, W2r, W2rT, vc, e_sp, compsT,
                                      Zdyn);
  // 2. G1+G3: 2048 fused tiles (128x128 + 1024 Z each), no pure-Z tail
  k_g13_z<<<2048, 512, 0, stream>>>(x_bf, W1eT, b1e, h_bf, W1rT, b1r, hr_bf,
                                    Zdyn);
  // 3. e_raw = h@W2e+b2e (f32, into d_out) + Z zidx [6912,11520)  — mod-10
  k_e_z<<<5120, 256, 0, stream>>>(h_bf, W2eT, b2e, e_f32, Zdyn);
  // 4. conc_raw = hr@W2r+b2r (f32, over dead h) + Z zidx [11520,16384)
  k_r_z<<<5376, 256, 0, stream>>>(hr_bf, W2rT, b2r, cr_f32, Zdyn);
  // 5. gate: conc = bf16(cr * sigmoid(A32*e - z)), in-place over Zdyn
  k_gate<<<4096, 256, 0, stream>>>(e_f32, cr_f32, Zdyn);
  // 6. out = conc @ comps
  k_gemm_out<<<dim3(Dn / 128, Bn / 128), 256, 0, stream>>>(Zdyn, compsT, out);
}

// Round 12
// 769.807 us; speedup vs baseline: 1.0971x; 1.0019x over previous
//
#include <hip/hip_runtime.h>
#include <hip/hip_bf16.h>
#include <stdint.h>

// Problem dims
#define Bn 16384
#define Cn 512
#define Dn 512
#define Hn 1024

// a = 1 - 0.95^32 (closed-form Langevin: u32 = -a*e + Z)
#define A32 0.80628851f

typedef __attribute__((ext_vector_type(8))) short bf16x8;   // 8 bf16 (4 VGPRs)
typedef __attribute__((ext_vector_type(4))) float f32x4;    // MFMA accum
typedef __attribute__((ext_vector_type(2))) float f32x2;    // packed fp32 pair

// f32 -> bf16 RTNE (manual; inputs are finite)
__device__ __forceinline__ ushort f2bf(float f) {
  uint32_t u = __float_as_uint(f);
  return (ushort)((u + 0x7fffu + ((u >> 16) & 1u)) >> 16);
}
__device__ __forceinline__ float b2f(ushort u) {
  return __uint_as_float((uint32_t)u << 16);
}

// global -> LDS direct (16B/lane). LDS dest is wave-uniform base + lane*16.
typedef __attribute__((address_space(3))) uint32_t lds_u32_t;
typedef const __attribute__((address_space(1))) uint32_t glb_u32_t;
__device__ __forceinline__ void gload16(const ushort* g, ushort* l) {
  __builtin_amdgcn_global_load_lds((glb_u32_t*)g, (lds_u32_t*)l, 16, 0, 0);
}

// ---------------------------------------------------------------------------
// COMPILE-TIME threefry2x32 key schedule (partitionable JAX, verified round 4)
// ---------------------------------------------------------------------------
constexpr uint32_t crotl(uint32_t v, int s) {
  return (v << s) | (v >> (32 - s));
}
struct TFOut { uint32_t w0, w1; };
constexpr TFOut ctf(uint32_t k0, uint32_t k1, uint32_t x0, uint32_t x1) {
  const uint32_t ks[3] = {k0, k1, k0 ^ k1 ^ 0x1BD11BDAu};
  const int rot[8] = {13, 15, 26, 6, 17, 29, 16, 24};
  uint32_t a = x0 + k0, b = x1 + k1;
  for (int g = 0; g < 5; ++g) {
    for (int i = 0; i < 4; ++i) {
      int r = rot[(g & 1) * 4 + i];
      a += b; b = crotl(b, r); b ^= a;
    }
    a += ks[(g + 1) % 3];
    b += ks[(g + 2) % 3] + (uint32_t)(g + 1);
  }
  return {a, b};
}
struct KeySched { uint32_t s[64]; uint32_t d[64]; };
constexpr KeySched make_keys() {
  KeySched K{};
  TFOut k1 = ctf(0u, 42u, 0u, 0u);  // split(key(42))[0]
  TFOut k2 = ctf(0u, 42u, 0u, 1u);  // split(key(42))[1]
  for (uint32_t t = 0; t < 32; ++t) {
    TFOut ws = ctf(k1.w0, k1.w1, 0u, t);
    K.s[2 * t] = ws.w0; K.s[2 * t + 1] = ws.w1;
    TFOut wd = ctf(k2.w0, k2.w1, 0u, t);
    K.d[2 * t] = wd.w0; K.d[2 * t + 1] = wd.w1;
  }
  return K;
}
// __constant__ so rolled loops can s_load keys (runtime-indexed, uniform).
__constant__ KeySched KS = make_keys();

__device__ __forceinline__ uint32_t rotl32(uint32_t v, int s) {
  return __builtin_rotateleft32(v, (uint32_t)s);
}
__device__ __forceinline__ uint32_t tf_xor(uint32_t K0, uint32_t K1,
                                           uint32_t KX, uint32_t j) {
  uint32_t a = K0, b = K1 + j;
#define TR(r) { a += b; b = rotl32(b, (r)); b ^= a; }
  TR(13) TR(15) TR(26) TR(6)   a += K1; b += KX + 1u;
  TR(17) TR(29) TR(16) TR(24)  a += KX; b += K0 + 2u;
  TR(13) TR(15) TR(26) TR(6)   a += K0; b += K1 + 3u;
  TR(17) TR(29) TR(16) TR(24)  a += K1; b += KX + 4u;
  TR(13) TR(15) TR(26) TR(6)   a += KX; b += K0 + 5u;
#undef TR
  return a ^ b;
}

// Exact (branchy) bits->normal — static-mask path (verified).
__device__ __forceinline__ float bits_to_normal(uint32_t bits) {
  float f = __uint_as_float((bits >> 9) | 0x3f800000u) - 1.0f;
  float x = f * 2.0f - 0x1.fffffep-1f;
  float w = -__logf(1.0f - x * x);
  float p;
  if (w < 5.0f) {
    w -= 2.5f;
    p =            2.81022636e-08f;
    p = fmaf(p, w, 3.43273939e-07f);
    p = fmaf(p, w, -3.5233877e-06f);
    p = fmaf(p, w, -4.39150654e-06f);
    p = fmaf(p, w, 0.00021858087f);
    p = fmaf(p, w, -0.00125372503f);
    p = fmaf(p, w, -0.00417768164f);
    p = fmaf(p, w, 0.246640727f);
    p = fmaf(p, w, 1.50140941f);
  } else {
    w = sqrtf(w) - 3.0f;
    p =            -0.000200214257f;
    p = fmaf(p, w, 0.000100950558f);
    p = fmaf(p, w, 0.00134934322f);
    p = fmaf(p, w, -0.00367342844f);
    p = fmaf(p, w, 0.00573950773f);
    p = fmaf(p, w, -0.0076224613f);
    p = fmaf(p, w, 0.00943887047f);
    p = fmaf(p, w, 1.00167406f);
    p = fmaf(p, w, 2.83297682f);
  }
  return 0x1.6a09e6p+0f * (p * x);
}

// ---------------------------------------------------------------------------
// One Langevin step for a 2-element chain pair — EXACT ops/order of the
// verified z_block body (bit-identical per element).
// ---------------------------------------------------------------------------
__device__ __forceinline__ void z_step(int t, uint32_t j0, uint32_t j1,
                                       float& z0, float& z1) {
  const uint32_t K0 = KS.d[2 * t], K1 = KS.d[2 * t + 1];
  const uint32_t KX = K0 ^ K1 ^ 0x1BD11BDAu;
  uint32_t a0 = K0, b0 = K1 + j0;
  uint32_t a1 = K0, b1 = K1 + j1;
#define R2(r)                                                  \
  a0 += b0; a1 += b1;                                          \
  b0 = rotl32(b0, (r)); b1 = rotl32(b1, (r));                  \
  b0 ^= a0; b1 ^= a1;
#define I2(p, q) a0 += (p); a1 += (p); b0 += (q); b1 += (q);
  R2(13) R2(15) R2(26) R2(6)  I2(K1, KX + 1u)
  R2(17) R2(29) R2(16) R2(24) I2(KX, K0 + 2u)
  R2(13) R2(15) R2(26) R2(6)  I2(K0, K1 + 3u)
  R2(17) R2(29) R2(16) R2(24) I2(K1, KX + 4u)
  R2(13) R2(15) R2(26) R2(6)  I2(KX, K0 + 5u)
#undef R2
#undef I2
  uint32_t s0 = a0 ^ b0, s1 = a1 ^ b1;
  float f0 = __uint_as_float((s0 >> 9) | 0x3f800000u) - 1.0f;
  float f1 = __uint_as_float((s1 >> 9) | 0x3f800000u) - 1.0f;
  float x0 = f0 * 2.0f - 0x1.fffffep-1f;
  float x1 = f1 * 2.0f - 0x1.fffffep-1f;
  float w0 = fminf(-__logf(fmaf(-x0, x0, 1.0f)), 5.0f) - 2.5f;
  float w1 = fminf(-__logf(fmaf(-x1, x1, 1.0f)), 5.0f) - 2.5f;
  f32x2 X = {x0, x1}, W = {w0, w1};
  f32x2 P = {2.81022636e-08f, 2.81022636e-08f};
  P = __builtin_elementwise_fma(P, W, (f32x2){3.43273939e-07f, 3.43273939e-07f});
  P = __builtin_elementwise_fma(P, W, (f32x2){-3.5233877e-06f, -3.5233877e-06f});
  P = __builtin_elementwise_fma(P, W, (f32x2){-4.39150654e-06f, -4.39150654e-06f});
  P = __builtin_elementwise_fma(P, W, (f32x2){0.00021858087f, 0.00021858087f});
  P = __builtin_elementwise_fma(P, W, (f32x2){-0.00125372503f, -0.00125372503f});
  P = __builtin_elementwise_fma(P, W, (f32x2){-0.00417768164f, -0.00417768164f});
  P = __builtin_elementwise_fma(P, W, (f32x2){0.246640727f, 0.246640727f});
  P = __builtin_elementwise_fma(P, W, (f32x2){1.50140941f, 1.50140941f});
  f32x2 Q = (P * X) * (f32x2){0.14142135f, 0.14142135f};  // 0.1*sqrt(2)
  z0 = fmaf(0.95f, z0, Q.x);
  z1 = fmaf(0.95f, z1, Q.y);
}

// ---------------------------------------------------------------------------
// Z block (256-thread form, verified): 512 elems at zidx*512.
// ---------------------------------------------------------------------------
__device__ __forceinline__ void z_block(ushort* __restrict__ Z, uint32_t zidx) {
  const uint32_t j0 = (zidx * 256u + threadIdx.x) * 2u;
  const uint32_t j1 = j0 + 1u;
  float z0 = 0.0f, z1 = 0.0f;
#pragma unroll 4
  for (int t = 0; t < 32; ++t) z_step(t, j0, j1, z0, z1);
  *(ushort2*)(Z + j0) = make_ushort2(f2bf(z0), f2bf(z1));
}

// 512-thread pure-Z unit (round-10 verified): 1024 elems at 1441792+u*1024.
__device__ __forceinline__ void z_unit512(ushort* __restrict__ Z, uint32_t u) {
  const uint32_t j0 = 1441792u + u * 1024u + (uint32_t)threadIdx.x * 2u;
  const uint32_t j1 = j0 + 1u;
  float z0 = 0.0f, z1 = 0.0f;
#pragma unroll 4
  for (int t = 0; t < 32; ++t) z_step(t, j0, j1, z0, z1);
  *(ushort2*)(Z + j0) = make_ushort2(f2bf(z0), f2bf(z1));
}

// ---------------------------------------------------------------------------
// PREP units: cvt_x + 4 LDS-tiled coalesced transposes + smask (verified).
// ---------------------------------------------------------------------------
__device__ __forceinline__ void transpose_tile(
    const float* __restrict__ in, ushort* __restrict__ out,
    int N, int K, int tIdx, float T[32][33]) {
  const int ntn = N / 32;
  const int tk = tIdx / ntn, tn = tIdx % ntn;
  const int tx = threadIdx.x & 31, ty = threadIdx.x >> 5;  // 32 x 8
  const int k0 = tk * 32, n0 = tn * 32;
#pragma unroll
  for (int r = 0; r < 32; r += 8)
    T[ty + r][tx] = in[(size_t)(k0 + ty + r) * N + n0 + tx];
  __syncthreads();
#pragma unroll
  for (int r = 0; r < 32; r += 8)
    out[(size_t)(n0 + ty + r) * K + k0 + tx] = f2bf(T[tx][ty + r]);
}

__device__ __forceinline__ void smask_block(
    const float* __restrict__ vc, const float* __restrict__ e_sp,
    ushort* __restrict__ compsT, int g) {
  uint32_t jj = (uint32_t)g * 256 + threadIdx.x;  // j = d*C + c
  uint32_t c = jj & (Cn - 1), d = jj >> 9;
  uint32_t ridx = c * Dn + d;
  float e = e_sp[ridx];
  float u = 0.0f;
#pragma unroll 4
  for (int t = 0; t < 32; ++t) {
    const uint32_t K0 = KS.s[2 * t], K1 = KS.s[2 * t + 1];
    uint32_t s = tf_xor(K0, K1, K0 ^ K1 ^ 0x1BD11BDAu, ridx);
    float n = bits_to_normal(s);
    u = (u - 0.05f * (u + e)) + 0.1f * n;
  }
  float gt = 1.0f / (1.0f + __expf(u));
  compsT[jj] = f2bf(fabsf(vc[ridx]) * gt);
}

// K1: prep (11264 units) + Z chunk (2816 x 512-elem blocks), mod-5.
__global__ __launch_bounds__(256) void k_prep_z(
    const float* __restrict__ x, ushort* __restrict__ x_bf,
    const float* __restrict__ W1e, ushort* __restrict__ W1eT,
    const float* __restrict__ W2e, ushort* __restrict__ W2eT,
    const float* __restrict__ W1r, ushort* __restrict__ W1rT,
    const float* __restrict__ W2r, ushort* __restrict__ W2rT,
    const float* __restrict__ vc, const float* __restrict__ e_sp,
    ushort* __restrict__ compsT, ushort* __restrict__ Zd) {
  __shared__ float T[32][33];
  const int pos = blockIdx.x;
  if ((pos % 5) == 4) {                         // 2816 Z blocks: zidx 0..2815
    z_block(Zd, (uint32_t)(pos / 5));
    return;
  }
  const int p = (pos / 5) * 4 + (pos % 5);      // 0..11263 prep units
  if (p < 8192) {
    int i = (p * 256 + threadIdx.x) * 4;
    float4 v = *(const float4*)(x + i);
    *(ushort4*)(x_bf + i) =
        make_ushort4(f2bf(v.x), f2bf(v.y), f2bf(v.z), f2bf(v.w));
  } else if (p < 8704) {
    transpose_tile(W1e, W1eT, Hn, Dn, p - 8192, T);   // [D][H] -> [H][D]
  } else if (p < 9216) {
    transpose_tile(W2e, W2eT, Cn, Hn, p - 8704, T);   // [H][C] -> [C][H]
  } else if (p < 9728) {
    transpose_tile(W1r, W1rT, Hn, Dn, p - 9216, T);
  } else if (p < 10240) {
    transpose_tile(W2r, W2rT, Cn, Hn, p - 9728, T);
  } else {
    smask_block(vc, e_sp, compsT, p - 10240);
  }
}

// ---------------------------------------------------------------------------
// FUSED GEMM+Z core (round-10/11 verified): 128x128 tile, 512 threads /
// 8 waves (each wave 64x32: wm=(w>>2)*64, wn=(w&3)*32 -> acc[4][2]).
// Single-buffered K-loop via global_load_lds; XOR-swizzled columns
// (conflicts = 0).  ZS Langevin steps interleaved per K-iter.
// ---------------------------------------------------------------------------
template <int KIT, int ZS>
__device__ __forceinline__ void gemm_z_fused(
    const ushort* __restrict__ A, const ushort* __restrict__ WT,
    int m0, int n0, int LD,
    ushort* __restrict__ AsL, ushort* __restrict__ BsL,
    f32x4 acc[4][2], uint32_t j0, uint32_t j1, float& z0, float& z1) {
  const int t = threadIdx.x;
  const int wave = t >> 6, lane = t & 63;
  const int row = t >> 2;                              // staging row 0..127
  const int col8 = ((t & 3) << 3) ^ (((t >> 3) & 3) << 3);    // swz'd src col
  const int wm = (wave >> 2) << 6, wn = (wave & 3) << 5;
  const int l15 = lane & 15, quad = lane >> 4;
  const int rc = (quad << 3) ^ (((l15 >> 1) & 3) << 3);       // swz'd read col

  const ushort* ga = A  + (size_t)(m0 + row) * LD + col8;
  const ushort* gb = WT + (size_t)(n0 + row) * LD + col8;
  ushort* la = AsL + wave * 512;           // wave-uniform dests (1 KB/wave)
  ushort* lb = BsL + wave * 512;

  for (int it = 0; it < KIT; ++it) {
    gload16(ga + it * 32, la);
    gload16(gb + it * 32, lb);
    __syncthreads();                       // drains vmcnt before barrier
    bf16x8 af[4], bfr[2];
#pragma unroll
    for (int i = 0; i < 4; ++i)
      af[i] = *(const bf16x8*)&AsL[(wm + i * 16 + l15) * 32 + rc];
#pragma unroll
    for (int j = 0; j < 2; ++j)
      bfr[j] = *(const bf16x8*)&BsL[(wn + j * 16 + l15) * 32 + rc];
#pragma unroll
    for (int i = 0; i < 4; ++i)
#pragma unroll
      for (int j = 0; j < 2; ++j)
        acc[i][j] = __builtin_amdgcn_mfma_f32_16x16x32_bf16(af[i], bfr[j],
                                                            acc[i][j], 0, 0, 0);
#pragma unroll
    for (int s = 0; s < ZS; ++s)           // Z VALU hides under MFMA drain
      z_step(it * ZS + s, j0, j1, z0, z1);
    __syncthreads();                       // protect LDS for next stage
  }
}

// TWO-PAIR fused core for K=1024 tiles: per K-iter, advance ONE step of
// EACH of two chain pairs -> per-iter profile (2 gloads, 8 MFMA, 2 z_steps,
// 2 barriers) is IDENTICAL to the verified g13 fused tile; tile hosts
// 2048 Z elems across 32 iters.  (r10's 1-pair KIT=32 had half the
// per-barrier Z density — that was its tax.)
template <int KIT>
__device__ __forceinline__ void gemm_z2_fused(
    const ushort* __restrict__ A, const ushort* __restrict__ WT,
    int m0, int n0, int LD,
    ushort* __restrict__ AsL, ushort* __restrict__ BsL,
    f32x4 acc[4][2], uint32_t j0, uint32_t j2,
    float& z0, float& z1, float& z2, float& z3) {
  const int t = threadIdx.x;
  const int wave = t >> 6, lane = t & 63;
  const int row = t >> 2;                              // staging row 0..127
  const int col8 = ((t & 3) << 3) ^ (((t >> 3) & 3) << 3);    // swz'd src col
  const int wm = (wave >> 2) << 6, wn = (wave & 3) << 5;
  const int l15 = lane & 15, quad = lane >> 4;
  const int rc = (quad << 3) ^ (((l15 >> 1) & 3) << 3);       // swz'd read col

  const ushort* ga = A  + (size_t)(m0 + row) * LD + col8;
  const ushort* gb = WT + (size_t)(n0 + row) * LD + col8;
  ushort* la = AsL + wave * 512;
  ushort* lb = BsL + wave * 512;

  for (int it = 0; it < KIT; ++it) {
    gload16(ga + it * 32, la);
    gload16(gb + it * 32, lb);
    __syncthreads();
    bf16x8 af[4], bfr[2];
#pragma unroll
    for (int i = 0; i < 4; ++i)
      af[i] = *(const bf16x8*)&AsL[(wm + i * 16 + l15) * 32 + rc];
#pragma unroll
    for (int j = 0; j < 2; ++j)
      bfr[j] = *(const bf16x8*)&BsL[(wn + j * 16 + l15) * 32 + rc];
#pragma unroll
    for (int i = 0; i < 4; ++i)
#pragma unroll
      for (int j = 0; j < 2; ++j)
        acc[i][j] = __builtin_amdgcn_mfma_f32_16x16x32_bf16(af[i], bfr[j],
                                                            acc[i][j], 0, 0, 0);
    z_step(it, j0, j0 + 1u, z0, z1);       // pair 0, step it
    z_step(it, j2, j2 + 1u, z2, z3);       // pair 1, step it
    __syncthreads();
  }
}

// K2: G1+G3 — 2048 fused tiles ONLY (each hosts 1024 Z elems,
// elems [1441792, 3538944)).  Round-11 verified verbatim.
__global__ __launch_bounds__(512, 6) void k_g13_z(
    const ushort* __restrict__ x_bf,
    const ushort* __restrict__ W1eT, const float* __restrict__ b1e,
    ushort* __restrict__ h,
    const ushort* __restrict__ W1rT, const float* __restrict__ b1r,
    ushort* __restrict__ hr, ushort* __restrict__ Zd) {
  __shared__ ushort AsL[4096];
  __shared__ ushort BsL[4096];
  const int pos = blockIdx.x;                  // 0..2047, all fused
  const uint32_t j0 = 1441792u + (uint32_t)pos * 1024u +
                      (uint32_t)threadIdx.x * 2u;
  const uint32_t j1 = j0 + 1u;
  float z0 = 0.0f, z1 = 0.0f;
  const int tg = pos >> 1;                     // 0..1023: 128 m x 8 n
  const int m0 = (tg >> 3) * 128, n0 = (tg & 7) * 128;
  const ushort* WTp = (pos & 1) ? W1rT : W1eT;
  const float*  bp  = (pos & 1) ? b1r  : b1e;
  ushort*       Op  = (pos & 1) ? hr   : h;
  f32x4 acc[4][2] = {};
  gemm_z_fused<16, 2>(x_bf, WTp, m0, n0, Dn, AsL, BsL, acc, j0, j1, z0, z1);
  *(ushort2*)(Zd + j0) = make_ushort2(f2bf(z0), f2bf(z1));
  const int wave = threadIdx.x >> 6, lane = threadIdx.x & 63;
  const int wm = (wave >> 2) << 6, wn = (wave & 3) << 5;
  const int quad = lane >> 4, l15 = lane & 15;
#pragma unroll
  for (int i = 0; i < 4; ++i)
#pragma unroll
    for (int j = 0; j < 2; ++j) {
      const int col = n0 + wn + j * 16 + l15;
      const float bv = bp[col];
#pragma unroll
      for (int r = 0; r < 4; ++r) {
        const int row = m0 + wm + i * 16 + quad * 4 + r;
        Op[(size_t)row * Hn + col] = f2bf(fmaxf(acc[i][j][r] + bv, 0.0f));
      }
    }
}

// K3e: e_raw — 512 two-pair fused tiles (2048 Z each, elems
// [3538944, 4587520)) + 1344 pure-Z units (u = 4096.., elems
// [5636096, 7012352)).
__global__ __launch_bounds__(512, 6) void k_e_z(
    const ushort* __restrict__ h, const ushort* __restrict__ W2eT,
    const float* __restrict__ b2e, float* __restrict__ e_out,
    ushort* __restrict__ Zd) {
  __shared__ ushort AsL[4096];
  __shared__ ushort BsL[4096];
  const int pos = blockIdx.x;                  // 0..1855
  if (pos >= 512) {                            // pure-Z: u 4096..5439
    z_unit512(Zd, 4096u + (uint32_t)(pos - 512));
    return;
  }
  const uint32_t j0 = 3538944u + (uint32_t)pos * 2048u +
                      (uint32_t)threadIdx.x * 2u;
  const uint32_t j2 = j0 + 1024u;
  float z0 = 0.0f, z1 = 0.0f, z2 = 0.0f, z3 = 0.0f;
  const int m0 = (pos >> 2) * 128, n0 = (pos & 3) * 128;
  f32x4 acc[4][2] = {};
  gemm_z2_fused<32>(h, W2eT, m0, n0, Hn, AsL, BsL, acc, j0, j2,
                    z0, z1, z2, z3);
  *(ushort2*)(Zd + j0) = make_ushort2(f2bf(z0), f2bf(z1));
  *(ushort2*)(Zd + j2) = make_ushort2(f2bf(z2), f2bf(z3));
  const int wave = threadIdx.x >> 6, lane = threadIdx.x & 63;
  const int wm = (wave >> 2) << 6, wn = (wave & 3) << 5;
  const int quad = lane >> 4, l15 = lane & 15;
#pragma unroll
  for (int i = 0; i < 4; ++i)
#pragma unroll
    for (int j = 0; j < 2; ++j) {
      const int col = n0 + wn + j * 16 + l15;
      const float bv = b2e[col];
#pragma unroll
      for (int r = 0; r < 4; ++r) {
        const int row = m0 + wm + i * 16 + quad * 4 + r;
        e_out[(size_t)row * Cn + col] = acc[i][j][r] + bv;
      }
    }
}

// K3r: conc_raw — 512 two-pair fused tiles (elems [4587520, 5636096)) +
// 1344 pure-Z units (u = 5440.., elems [7012352, 8388608)).
__global__ __launch_bounds__(512, 6) void k_r_z(
    const ushort* __restrict__ hr, const ushort* __restrict__ W2rT,
    const float* __restrict__ b2r, float* __restrict__ cr_out,
    ushort* __restrict__ Zd) {
  __shared__ ushort AsL[4096];
  __shared__ ushort BsL[4096];
  const int pos = blockIdx.x;                  // 0..1855
  if (pos >= 512) {                            // pure-Z: u 5440..6783
    z_unit512(Zd, 5440u + (uint32_t)(pos - 512));
    return;
  }
  const uint32_t j0 = 4587520u + (uint32_t)pos * 2048u +
                      (uint32_t)threadIdx.x * 2u;
  const uint32_t j2 = j0 + 1024u;
  float z0 = 0.0f, z1 = 0.0f, z2 = 0.0f, z3 = 0.0f;
  const int m0 = (pos >> 2) * 128, n0 = (pos & 3) * 128;
  f32x4 acc[4][2] = {};
  gemm_z2_fused<32>(hr, W2rT, m0, n0, Hn, AsL, BsL, acc, j0, j2,
                    z0, z1, z2, z3);
  *(ushort2*)(Zd + j0) = make_ushort2(f2bf(z0), f2bf(z1));
  *(ushort2*)(Zd + j2) = make_ushort2(f2bf(z2), f2bf(z3));
  const int wave = threadIdx.x >> 6, lane = threadIdx.x & 63;
  const int wm = (wave >> 2) << 6, wn = (wave & 3) << 5;
  const int quad = lane >> 4, l15 = lane & 15;
#pragma unroll
  for (int i = 0; i < 4; ++i)
#pragma unroll
    for (int j = 0; j < 2; ++j) {
      const int col = n0 + wn + j * 16 + l15;
      const float bv = b2r[col];
#pragma unroll
      for (int r = 0; r < 4; ++r) {
        const int row = m0 + wm + i * 16 + quad * 4 + r;
        cr_out[(size_t)row * Cn + col] = acc[i][j][r] + bv;
      }
    }
}

// ---------------------------------------------------------------------------
// K4: gate apply (elementwise).  conc = bf16(cr * sigmoid(A32*e - z)).
// Identical f32 arithmetic to the former k_dgemm epilogue.
// ---------------------------------------------------------------------------
__global__ __launch_bounds__(256) void k_gate(
    const float* __restrict__ e, const float* __restrict__ cr,
    ushort* __restrict__ Z) {
  const size_t i = ((size_t)blockIdx.x * 256u + threadIdx.x) * 8u;
  uint4 zv = *(const uint4*)(Z + i);
  ushort zs[8];
  *(uint4*)zs = zv;
  float ee[8], cc[8];
  *(float4*)(ee)     = *(const float4*)(e + i);
  *(float4*)(ee + 4) = *(const float4*)(e + i + 4);
  *(float4*)(cc)     = *(const float4*)(cr + i);
  *(float4*)(cc + 4) = *(const float4*)(cr + i + 4);
  ushort os[8];
#pragma unroll
  for (int k = 0; k < 8; ++k) {
    float z = b2f(zs[k]);
    float g = 1.0f / (1.0f + __expf(z - A32 * ee[k]));
    os[k] = f2bf(cc[k] * g);
  }
  *(uint4*)(Z + i) = *(uint4*)os;
}

// ---------------------------------------------------------------------------
// K5: out = conc @ comps — 128x128 double-buffered core (round-7 verified):
// counted vmcnt + raw s_barrier; sched_barrier(0) after each waitcnt.
// ---------------------------------------------------------------------------
__device__ __forceinline__ void stage4(
    const ushort* ga0, const ushort* ga1,
    const ushort* gb0, const ushort* gb1,
    int k, ushort* As, ushort* Bs, int wo) {
  gload16(ga0 + k, As + wo);
  gload16(ga1 + k, As + 2048 + wo);
  gload16(gb0 + k, Bs + wo);
  gload16(gb1 + k, Bs + 2048 + wo);
}

__device__ __forceinline__ void mfma16(
    const ushort* Ac, const ushort* Bc,
    int wm, int wn, int l15, int rc, f32x4 acc[4][4]) {
  bf16x8 af[4], bfr[4];
#pragma unroll
  for (int i = 0; i < 4; ++i) {
    af[i]  = *(const bf16x8*)&Ac[(wm + i * 16 + l15) * 32 + rc];
    bfr[i] = *(const bf16x8*)&Bc[(wn + i * 16 + l15) * 32 + rc];
  }
#pragma unroll
  for (int i = 0; i < 4; ++i)
#pragma unroll
    for (int j = 0; j < 4; ++j)
      acc[i][j] = __builtin_amdgcn_mfma_f32_16x16x32_bf16(af[i], bfr[j],
                                                          acc[i][j], 0, 0, 0);
}

__global__ __launch_bounds__(256) void k_gemm_out(
    const ushort* __restrict__ A, const ushort* __restrict__ WT,
    float* __restrict__ Out) {
  __shared__ ushort As0[4096];
  __shared__ ushort Bs0[4096];
  __shared__ ushort As1[4096];
  __shared__ ushort Bs1[4096];
  const int t = threadIdx.x;
  const int m0 = blockIdx.y * 128, n0 = blockIdx.x * 128;
  const int wave = t >> 6, lane = t & 63;
  const int row = t >> 2;
  const int col8 = ((t & 3) << 3) ^ (((t >> 3) & 3) << 3);
  const int wm = (wave >> 1) << 6, wn = (wave & 1) << 6;
  const int quad = lane >> 4, l15 = lane & 15;
  const int rc = (quad << 3) ^ (((l15 >> 1) & 3) << 3);
  const int wo = wave * 512;

  const ushort* ga0 = A  + (size_t)(m0 + row) * Cn + col8;
  const ushort* ga1 = A  + (size_t)(m0 + 64 + row) * Cn + col8;
  const ushort* gb0 = WT + (size_t)(n0 + row) * Cn + col8;
  const ushort* gb1 = WT + (size_t)(n0 + 64 + row) * Cn + col8;

  f32x4 acc[4][4] = {};
  stage4(ga0, ga1, gb0, gb1, 0, As0, Bs0, wo);
  for (int k0 = 0; k0 < Cn; k0 += 64) {
    stage4(ga0, ga1, gb0, gb1, k0 + 32, As1, Bs1, wo);
    asm volatile("s_waitcnt vmcnt(4)" ::: "memory");
    __builtin_amdgcn_sched_barrier(0);
    __builtin_amdgcn_s_barrier();
    mfma16(As0, Bs0, wm, wn, l15, rc, acc);
    __builtin_amdgcn_s_barrier();
    if (k0 + 64 < Cn) {
      stage4(ga0, ga1, gb0, gb1, k0 + 64, As0, Bs0, wo);
      asm volatile("s_waitcnt vmcnt(4)" ::: "memory");
    } else {
      asm volatile("s_waitcnt vmcnt(0)" ::: "memory");
    }
    __builtin_amdgcn_sched_barrier(0);
    __builtin_amdgcn_s_barrier();
    mfma16(As1, Bs1, wm, wn, l15, rc, acc);
    __builtin_amdgcn_s_barrier();
  }
#pragma unroll
  for (int i = 0; i < 4; ++i)
#pragma unroll
    for (int j = 0; j < 4; ++j) {
      const int col = n0 + wn + j * 16 + l15;
#pragma unroll
      for (int r = 0; r < 4; ++r) {
        const int row2 = m0 + wm + i * 16 + quad * 4 + r;
        Out[(size_t)row2 * Dn + col] = acc[i][j][r];
      }
    }
}

// ---------------------------------------------------------------------------
extern "C" void kernel_launch(void* const* d_in, const int* in_sizes, int n_in,
                              void* d_out, int out_size, void* d_ws, size_t ws_size,
                              hipStream_t stream) {
  const float* x    = (const float*)d_in[0];
  const float* vc   = (const float*)d_in[1];
  const float* e_sp = (const float*)d_in[2];
  const float* W1e  = (const float*)d_in[3];
  const float* b1e  = (const float*)d_in[4];
  const float* W2e  = (const float*)d_in[5];
  const float* b2e  = (const float*)d_in[6];
  const float* W1r  = (const float*)d_in[7];
  const float* b1r  = (const float*)d_in[8];
  const float* W2r  = (const float*)d_in[9];
  const float* b2r  = (const float*)d_in[10];
  float* out = (float*)d_out;

  // Workspace (88 MiB high-water, unchanged):
  //   4096    W1eT | +1M W2eT | +2M W1rT | +3M W2rT  (bf16 transposed)
  //   +4M     compsT [D][C] bf16
  //   8M      Zdyn [B][C] bf16 (16 MiB): z -> (gate) -> conc in-place
  //   24M     h  [B][H] bf16 (32 MiB); dead after k_e_z -> cr_f32 [B][C] f32
  //   56M     hr [B][H] bf16 (32 MiB)
  // d_out (32 MiB): x_bf scratch (16 MiB) until k_g13_z; then e_raw f32
  //   (32 MiB) until k_gate; then final out.
  // Z element coverage (complete, disjoint, total 8388608):
  //   prep  zidx 0..2815 x512            = [0,       1441792)
  //   g13   2048 fused x1024             = [1441792, 3538944)
  //   e     512 fused x2048              = [3538944, 4587520)
  //   r     512 fused x2048              = [4587520, 5636096)
  //   e     1344 units (u 4096..5439)    = [5636096, 7012352)
  //   r     1344 units (u 5440..6783)    = [7012352, 8388608)
  char* ws = (char*)d_ws;
  ushort* W1eT   = (ushort*)(ws + (1u << 12));
  ushort* W2eT   = (ushort*)(ws + (1u << 12) + (1u << 20));
  ushort* W1rT   = (ushort*)(ws + (1u << 12) + (2u << 20));
  ushort* W2rT   = (ushort*)(ws + (1u << 12) + (3u << 20));
  ushort* compsT = (ushort*)(ws + (1u << 12) + (4u << 20));
  ushort* Zdyn   = (ushort*)(ws + (8u << 20));
  ushort* h_bf   = (ushort*)(ws + (24u << 20));
  ushort* hr_bf  = (ushort*)(ws + (56u << 20));
  float*  cr_f32 = (float*)(ws + (24u << 20));   // over dead h_bf
  ushort* x_bf   = (ushort*)d_out;               // scratch until k_e_z
  float*  e_f32  = (float*)d_out;                // after k_g13_z

  // 1. prep (cvt_x, 4 transposes, smask) + Z elems [0, 1441792)
  k_prep_z<<<14080, 256, 0, stream>>>(x, x_bf, W1e, W1eT, W2e, W2eT,
                                      W1r, W1rT, W2r, W2rT, vc, e_sp, compsT,
                                      Zdyn);
  // 2. G1+G3: 2048 fused tiles (128x128 + 1024 Z each)
  k_g13_z<<<2048, 512, 0, stream>>>(x_bf, W1eT, b1e, h_bf, W1rT, b1r, hr_bf,
                                    Zdyn);
  // 3. e_raw: 512 two-pair fused tiles + 1344 pure-Z units
  k_e_z<<<1856, 512, 0, stream>>>(h_bf, W2eT, b2e, e_f32, Zdyn);
  // 4. conc_raw: 512 two-pair fused tiles + 1344 pure-Z units
  k_r_z<<<1856, 512, 0, stream>>>(hr_bf, W2rT, b2r, cr_f32, Zdyn);
  // 5. gate: conc = bf16(cr * sigmoid(A32*e - z)), in-place over Zdyn
  k_gate<<<4096, 256, 0, stream>>>(e_f32, cr_f32, Zdyn);
  // 6. out = conc @ comps
  k_gemm_out<<<dim3(Dn / 128, Bn / 128), 256, 0, stream>>>(Zdyn, compsT, out);
}

// Round 13
// 753.000 us; speedup vs baseline: 1.1216x; 1.0223x over previous
//
#include <hip/hip_runtime.h>
#include <hip/hip_bf16.h>
#include <stdint.h>

// Problem dims
#define Bn 16384
#define Cn 512
#define Dn 512
#define Hn 1024

// a = 1 - 0.95^32 (closed-form Langevin: u32 = -a*e + Z)
#define A32 0.80628851f

typedef __attribute__((ext_vector_type(8))) short bf16x8;   // 8 bf16 (4 VGPRs)
typedef __attribute__((ext_vector_type(4))) float f32x4;    // MFMA accum
typedef __attribute__((ext_vector_type(2))) float f32x2;    // packed fp32 pair

// f32 -> bf16 RTNE (manual; inputs are finite)
__device__ __forceinline__ ushort f2bf(float f) {
  uint32_t u = __float_as_uint(f);
  return (ushort)((u + 0x7fffu + ((u >> 16) & 1u)) >> 16);
}
__device__ __forceinline__ float b2f(ushort u) {
  return __uint_as_float((uint32_t)u << 16);
}

// global -> LDS direct (16B/lane). LDS dest is wave-uniform base + lane*16.
typedef __attribute__((address_space(3))) uint32_t lds_u32_t;
typedef const __attribute__((address_space(1))) uint32_t glb_u32_t;
__device__ __forceinline__ void gload16(const ushort* g, ushort* l) {
  __builtin_amdgcn_global_load_lds((glb_u32_t*)g, (lds_u32_t*)l, 16, 0, 0);
}

// ---------------------------------------------------------------------------
// COMPILE-TIME threefry2x32 key schedule (partitionable JAX, verified round 4)
// ---------------------------------------------------------------------------
constexpr uint32_t crotl(uint32_t v, int s) {
  return (v << s) | (v >> (32 - s));
}
struct TFOut { uint32_t w0, w1; };
constexpr TFOut ctf(uint32_t k0, uint32_t k1, uint32_t x0, uint32_t x1) {
  const uint32_t ks[3] = {k0, k1, k0 ^ k1 ^ 0x1BD11BDAu};
  const int rot[8] = {13, 15, 26, 6, 17, 29, 16, 24};
  uint32_t a = x0 + k0, b = x1 + k1;
  for (int g = 0; g < 5; ++g) {
    for (int i = 0; i < 4; ++i) {
      int r = rot[(g & 1) * 4 + i];
      a += b; b = crotl(b, r); b ^= a;
    }
    a += ks[(g + 1) % 3];
    b += ks[(g + 2) % 3] + (uint32_t)(g + 1);
  }
  return {a, b};
}
struct KeySched { uint32_t s[64]; uint32_t d[64]; };
constexpr KeySched make_keys() {
  KeySched K{};
  TFOut k1 = ctf(0u, 42u, 0u, 0u);  // split(key(42))[0]
  TFOut k2 = ctf(0u, 42u, 0u, 1u);  // split(key(42))[1]
  for (uint32_t t = 0; t < 32; ++t) {
    TFOut ws = ctf(k1.w0, k1.w1, 0u, t);
    K.s[2 * t] = ws.w0; K.s[2 * t + 1] = ws.w1;
    TFOut wd = ctf(k2.w0, k2.w1, 0u, t);
    K.d[2 * t] = wd.w0; K.d[2 * t + 1] = wd.w1;
  }
  return K;
}
// __constant__ so rolled loops can s_load keys (runtime-indexed, uniform).
__constant__ KeySched KS = make_keys();

__device__ __forceinline__ uint32_t rotl32(uint32_t v, int s) {
  return __builtin_rotateleft32(v, (uint32_t)s);
}
__device__ __forceinline__ uint32_t tf_xor(uint32_t K0, uint32_t K1,
                                           uint32_t KX, uint32_t j) {
  uint32_t a = K0, b = K1 + j;
#define TR(r) { a += b; b = rotl32(b, (r)); b ^= a; }
  TR(13) TR(15) TR(26) TR(6)   a += K1; b += KX + 1u;
  TR(17) TR(29) TR(16) TR(24)  a += KX; b += K0 + 2u;
  TR(13) TR(15) TR(26) TR(6)   a += K0; b += K1 + 3u;
  TR(17) TR(29) TR(16) TR(24)  a += K1; b += KX + 4u;
  TR(13) TR(15) TR(26) TR(6)   a += KX; b += K0 + 5u;
#undef TR
  return a ^ b;
}

// Exact (branchy) bits->normal — static-mask path (verified).
__device__ __forceinline__ float bits_to_normal(uint32_t bits) {
  float f = __uint_as_float((bits >> 9) | 0x3f800000u) - 1.0f;
  float x = f * 2.0f - 0x1.fffffep-1f;
  float w = -__logf(1.0f - x * x);
  float p;
  if (w < 5.0f) {
    w -= 2.5f;
    p =            2.81022636e-08f;
    p = fmaf(p, w, 3.43273939e-07f);
    p = fmaf(p, w, -3.5233877e-06f);
    p = fmaf(p, w, -4.39150654e-06f);
    p = fmaf(p, w, 0.00021858087f);
    p = fmaf(p, w, -0.00125372503f);
    p = fmaf(p, w, -0.00417768164f);
    p = fmaf(p, w, 0.246640727f);
    p = fmaf(p, w, 1.50140941f);
  } else {
    w = sqrtf(w) - 3.0f;
    p =            -0.000200214257f;
    p = fmaf(p, w, 0.000100950558f);
    p = fmaf(p, w, 0.00134934322f);
    p = fmaf(p, w, -0.00367342844f);
    p = fmaf(p, w, 0.00573950773f);
    p = fmaf(p, w, -0.0076224613f);
    p = fmaf(p, w, 0.00943887047f);
    p = fmaf(p, w, 1.00167406f);
    p = fmaf(p, w, 2.83297682f);
  }
  return 0x1.6a09e6p+0f * (p * x);
}

// ---------------------------------------------------------------------------
// One Langevin step for a 2-element chain pair — EXACT ops/order of the
// verified z_block body (bit-identical per element).
// ---------------------------------------------------------------------------
__device__ __forceinline__ void z_step(int t, uint32_t j0, uint32_t j1,
                                       float& z0, float& z1) {
  const uint32_t K0 = KS.d[2 * t], K1 = KS.d[2 * t + 1];
  const uint32_t KX = K0 ^ K1 ^ 0x1BD11BDAu;
  uint32_t a0 = K0, b0 = K1 + j0;
  uint32_t a1 = K0, b1 = K1 + j1;
#define R2(r)                                                  \
  a0 += b0; a1 += b1;                                          \
  b0 = rotl32(b0, (r)); b1 = rotl32(b1, (r));                  \
  b0 ^= a0; b1 ^= a1;
#define I2(p, q) a0 += (p); a1 += (p); b0 += (q); b1 += (q);
  R2(13) R2(15) R2(26) R2(6)  I2(K1, KX + 1u)
  R2(17) R2(29) R2(16) R2(24) I2(KX, K0 + 2u)
  R2(13) R2(15) R2(26) R2(6)  I2(K0, K1 + 3u)
  R2(17) R2(29) R2(16) R2(24) I2(K1, KX + 4u)
  R2(13) R2(15) R2(26) R2(6)  I2(KX, K0 + 5u)
#undef R2
#undef I2
  uint32_t s0 = a0 ^ b0, s1 = a1 ^ b1;
  float f0 = __uint_as_float((s0 >> 9) | 0x3f800000u) - 1.0f;
  float f1 = __uint_as_float((s1 >> 9) | 0x3f800000u) - 1.0f;
  float x0 = f0 * 2.0f - 0x1.fffffep-1f;
  float x1 = f1 * 2.0f - 0x1.fffffep-1f;
  float w0 = fminf(-__logf(fmaf(-x0, x0, 1.0f)), 5.0f) - 2.5f;
  float w1 = fminf(-__logf(fmaf(-x1, x1, 1.0f)), 5.0f) - 2.5f;
  f32x2 X = {x0, x1}, W = {w0, w1};
  f32x2 P = {2.81022636e-08f, 2.81022636e-08f};
  P = __builtin_elementwise_fma(P, W, (f32x2){3.43273939e-07f, 3.43273939e-07f});
  P = __builtin_elementwise_fma(P, W, (f32x2){-3.5233877e-06f, -3.5233877e-06f});
  P = __builtin_elementwise_fma(P, W, (f32x2){-4.39150654e-06f, -4.39150654e-06f});
  P = __builtin_elementwise_fma(P, W, (f32x2){0.00021858087f, 0.00021858087f});
  P = __builtin_elementwise_fma(P, W, (f32x2){-0.00125372503f, -0.00125372503f});
  P = __builtin_elementwise_fma(P, W, (f32x2){-0.00417768164f, -0.00417768164f});
  P = __builtin_elementwise_fma(P, W, (f32x2){0.246640727f, 0.246640727f});
  P = __builtin_elementwise_fma(P, W, (f32x2){1.50140941f, 1.50140941f});
  f32x2 Q = (P * X) * (f32x2){0.14142135f, 0.14142135f};  // 0.1*sqrt(2)
  z0 = fmaf(0.95f, z0, Q.x);
  z1 = fmaf(0.95f, z1, Q.y);
}

// ---------------------------------------------------------------------------
// Z block (256-thread form, verified): 512 elems at zidx*512.
// ---------------------------------------------------------------------------
__device__ __forceinline__ void z_block(ushort* __restrict__ Z, uint32_t zidx) {
  const uint32_t j0 = (zidx * 256u + threadIdx.x) * 2u;
  const uint32_t j1 = j0 + 1u;
  float z0 = 0.0f, z1 = 0.0f;
#pragma unroll 4
  for (int t = 0; t < 32; ++t) z_step(t, j0, j1, z0, z1);
  *(ushort2*)(Z + j0) = make_ushort2(f2bf(z0), f2bf(z1));
}

// 512-thread pure-Z unit (round-10 verified): 1024 elems at 1441792+u*1024.
__device__ __forceinline__ void z_unit512(ushort* __restrict__ Z, uint32_t u) {
  const uint32_t j0 = 1441792u + u * 1024u + (uint32_t)threadIdx.x * 2u;
  const uint32_t j1 = j0 + 1u;
  float z0 = 0.0f, z1 = 0.0f;
#pragma unroll 4
  for (int t = 0; t < 32; ++t) z_step(t, j0, j1, z0, z1);
  *(ushort2*)(Z + j0) = make_ushort2(f2bf(z0), f2bf(z1));
}

// ---------------------------------------------------------------------------
// PREP units: cvt_x + 4 LDS-tiled coalesced transposes + smask (verified).
// ---------------------------------------------------------------------------
__device__ __forceinline__ void transpose_tile(
    const float* __restrict__ in, ushort* __restrict__ out,
    int N, int K, int tIdx, float T[32][33]) {
  const int ntn = N / 32;
  const int tk = tIdx / ntn, tn = tIdx % ntn;
  const int tx = threadIdx.x & 31, ty = threadIdx.x >> 5;  // 32 x 8
  const int k0 = tk * 32, n0 = tn * 32;
#pragma unroll
  for (int r = 0; r < 32; r += 8)
    T[ty + r][tx] = in[(size_t)(k0 + ty + r) * N + n0 + tx];
  __syncthreads();
#pragma unroll
  for (int r = 0; r < 32; r += 8)
    out[(size_t)(n0 + ty + r) * K + k0 + tx] = f2bf(T[tx][ty + r]);
}

__device__ __forceinline__ void smask_block(
    const float* __restrict__ vc, const float* __restrict__ e_sp,
    ushort* __restrict__ compsT, int g) {
  uint32_t jj = (uint32_t)g * 256 + threadIdx.x;  // j = d*C + c
  uint32_t c = jj & (Cn - 1), d = jj >> 9;
  uint32_t ridx = c * Dn + d;
  float e = e_sp[ridx];
  float u = 0.0f;
#pragma unroll 4
  for (int t = 0; t < 32; ++t) {
    const uint32_t K0 = KS.s[2 * t], K1 = KS.s[2 * t + 1];
    uint32_t s = tf_xor(K0, K1, K0 ^ K1 ^ 0x1BD11BDAu, ridx);
    float n = bits_to_normal(s);
    u = (u - 0.05f * (u + e)) + 0.1f * n;
  }
  float gt = 1.0f / (1.0f + __expf(u));
  compsT[jj] = f2bf(fabsf(vc[ridx]) * gt);
}

// K1: prep (11264 units) + Z chunk (2816 x 512-elem blocks), mod-5.
__global__ __launch_bounds__(256) void k_prep_z(
    const float* __restrict__ x, ushort* __restrict__ x_bf,
    const float* __restrict__ W1e, ushort* __restrict__ W1eT,
    const float* __restrict__ W2e, ushort* __restrict__ W2eT,
    const float* __restrict__ W1r, ushort* __restrict__ W1rT,
    const float* __restrict__ W2r, ushort* __restrict__ W2rT,
    const float* __restrict__ vc, const float* __restrict__ e_sp,
    ushort* __restrict__ compsT, ushort* __restrict__ Zd) {
  __shared__ float T[32][33];
  const int pos = blockIdx.x;
  if ((pos % 5) == 4) {                         // 2816 Z blocks: zidx 0..2815
    z_block(Zd, (uint32_t)(pos / 5));
    return;
  }
  const int p = (pos / 5) * 4 + (pos % 5);      // 0..11263 prep units
  if (p < 8192) {
    int i = (p * 256 + threadIdx.x) * 4;
    float4 v = *(const float4*)(x + i);
    *(ushort4*)(x_bf + i) =
        make_ushort4(f2bf(v.x), f2bf(v.y), f2bf(v.z), f2bf(v.w));
  } else if (p < 8704) {
    transpose_tile(W1e, W1eT, Hn, Dn, p - 8192, T);   // [D][H] -> [H][D]
  } else if (p < 9216) {
    transpose_tile(W2e, W2eT, Cn, Hn, p - 8704, T);   // [H][C] -> [C][H]
  } else if (p < 9728) {
    transpose_tile(W1r, W1rT, Hn, Dn, p - 9216, T);
  } else if (p < 10240) {
    transpose_tile(W2r, W2rT, Cn, Hn, p - 9728, T);
  } else {
    smask_block(vc, e_sp, compsT, p - 10240);
  }
}

// ---------------------------------------------------------------------------
// FUSED GEMM+Z core (round-10/11 verified): 128x128 tile, 512 threads /
// 8 waves (each wave 64x32: wm=(w>>2)*64, wn=(w&3)*32 -> acc[4][2]).
// Single-buffered K-loop via global_load_lds; XOR-swizzled columns
// (conflicts = 0).  ZS Langevin steps interleaved per K-iter.
// ---------------------------------------------------------------------------
template <int KIT, int ZS>
__device__ __forceinline__ void gemm_z_fused(
    const ushort* __restrict__ A, const ushort* __restrict__ WT,
    int m0, int n0, int LD,
    ushort* __restrict__ AsL, ushort* __restrict__ BsL,
    f32x4 acc[4][2], uint32_t j0, uint32_t j1, float& z0, float& z1) {
  const int t = threadIdx.x;
  const int wave = t >> 6, lane = t & 63;
  const int row = t >> 2;                              // staging row 0..127
  const int col8 = ((t & 3) << 3) ^ (((t >> 3) & 3) << 3);    // swz'd src col
  const int wm = (wave >> 2) << 6, wn = (wave & 3) << 5;
  const int l15 = lane & 15, quad = lane >> 4;
  const int rc = (quad << 3) ^ (((l15 >> 1) & 3) << 3);       // swz'd read col

  const ushort* ga = A  + (size_t)(m0 + row) * LD + col8;
  const ushort* gb = WT + (size_t)(n0 + row) * LD + col8;
  ushort* la = AsL + wave * 512;           // wave-uniform dests (1 KB/wave)
  ushort* lb = BsL + wave * 512;

  for (int it = 0; it < KIT; ++it) {
    gload16(ga + it * 32, la);
    gload16(gb + it * 32, lb);
    __syncthreads();                       // drains vmcnt before barrier
    bf16x8 af[4], bfr[2];
#pragma unroll
    for (int i = 0; i < 4; ++i)
      af[i] = *(const bf16x8*)&AsL[(wm + i * 16 + l15) * 32 + rc];
#pragma unroll
    for (int j = 0; j < 2; ++j)
      bfr[j] = *(const bf16x8*)&BsL[(wn + j * 16 + l15) * 32 + rc];
#pragma unroll
    for (int i = 0; i < 4; ++i)
#pragma unroll
      for (int j = 0; j < 2; ++j)
        acc[i][j] = __builtin_amdgcn_mfma_f32_16x16x32_bf16(af[i], bfr[j],
                                                            acc[i][j], 0, 0, 0);
#pragma unroll
    for (int s = 0; s < ZS; ++s)           // Z VALU hides under MFMA drain
      z_step(it * ZS + s, j0, j1, z0, z1);
    __syncthreads();                       // protect LDS for next stage
  }
}

// TWO-PAIR fused core for K=1024 tiles (round-12 verified): per K-iter,
// advance ONE step of EACH of two chain pairs -> per-iter profile
// (2 gloads, 8 MFMA, 2 z_steps, 2 barriers) identical to the g13 tile;
// tile hosts 2048 Z elems across 32 iters.
template <int KIT>
__device__ __forceinline__ void gemm_z2_fused(
    const ushort* __restrict__ A, const ushort* __restrict__ WT,
    int m0, int n0, int LD,
    ushort* __restrict__ AsL, ushort* __restrict__ BsL,
    f32x4 acc[4][2], uint32_t j0, uint32_t j2,
    float& z0, float& z1, float& z2, float& z3) {
  const int t = threadIdx.x;
  const int wave = t >> 6, lane = t & 63;
  const int row = t >> 2;                              // staging row 0..127
  const int col8 = ((t & 3) << 3) ^ (((t >> 3) & 3) << 3);    // swz'd src col
  const int wm = (wave >> 2) << 6, wn = (wave & 3) << 5;
  const int l15 = lane & 15, quad = lane >> 4;
  const int rc = (quad << 3) ^ (((l15 >> 1) & 3) << 3);       // swz'd read col

  const ushort* ga = A  + (size_t)(m0 + row) * LD + col8;
  const ushort* gb = WT + (size_t)(n0 + row) * LD + col8;
  ushort* la = AsL + wave * 512;
  ushort* lb = BsL + wave * 512;

  for (int it = 0; it < KIT; ++it) {
    gload16(ga + it * 32, la);
    gload16(gb + it * 32, lb);
    __syncthreads();
    bf16x8 af[4], bfr[2];
#pragma unroll
    for (int i = 0; i < 4; ++i)
      af[i] = *(const bf16x8*)&AsL[(wm + i * 16 + l15) * 32 + rc];
#pragma unroll
    for (int j = 0; j < 2; ++j)
      bfr[j] = *(const bf16x8*)&BsL[(wn + j * 16 + l15) * 32 + rc];
#pragma unroll
    for (int i = 0; i < 4; ++i)
#pragma unroll
      for (int j = 0; j < 2; ++j)
        acc[i][j] = __builtin_amdgcn_mfma_f32_16x16x32_bf16(af[i], bfr[j],
                                                            acc[i][j], 0, 0, 0);
    z_step(it, j0, j0 + 1u, z0, z1);       // pair 0, step it
    z_step(it, j2, j2 + 1u, z2, z3);       // pair 1, step it
    __syncthreads();
  }
}

// K2: G1+G3 — 2048 fused tiles ONLY (each hosts 1024 Z elems,
// elems [1441792, 3538944)).  Round-11/12 verified verbatim.
__global__ __launch_bounds__(512, 6) void k_g13_z(
    const ushort* __restrict__ x_bf,
    const ushort* __restrict__ W1eT, const float* __restrict__ b1e,
    ushort* __restrict__ h,
    const ushort* __restrict__ W1rT, const float* __restrict__ b1r,
    ushort* __restrict__ hr, ushort* __restrict__ Zd) {
  __shared__ ushort AsL[4096];
  __shared__ ushort BsL[4096];
  const int pos = blockIdx.x;                  // 0..2047, all fused
  const uint32_t j0 = 1441792u + (uint32_t)pos * 1024u +
                      (uint32_t)threadIdx.x * 2u;
  const uint32_t j1 = j0 + 1u;
  float z0 = 0.0f, z1 = 0.0f;
  const int tg = pos >> 1;                     // 0..1023: 128 m x 8 n
  const int m0 = (tg >> 3) * 128, n0 = (tg & 7) * 128;
  const ushort* WTp = (pos & 1) ? W1rT : W1eT;
  const float*  bp  = (pos & 1) ? b1r  : b1e;
  ushort*       Op  = (pos & 1) ? hr   : h;
  f32x4 acc[4][2] = {};
  gemm_z_fused<16, 2>(x_bf, WTp, m0, n0, Dn, AsL, BsL, acc, j0, j1, z0, z1);
  *(ushort2*)(Zd + j0) = make_ushort2(f2bf(z0), f2bf(z1));
  const int wave = threadIdx.x >> 6, lane = threadIdx.x & 63;
  const int wm = (wave >> 2) << 6, wn = (wave & 3) << 5;
  const int quad = lane >> 4, l15 = lane & 15;
#pragma unroll
  for (int i = 0; i < 4; ++i)
#pragma unroll
    for (int j = 0; j < 2; ++j) {
      const int col = n0 + wn + j * 16 + l15;
      const float bv = bp[col];
#pragma unroll
      for (int r = 0; r < 4; ++r) {
        const int row = m0 + wm + i * 16 + quad * 4 + r;
        Op[(size_t)row * Hn + col] = f2bf(fmaxf(acc[i][j][r] + bv, 0.0f));
      }
    }
}

// K3: MERGED e_raw + conc_raw — 1024 two-pair fused tiles (alternating
// e/r by pos parity; 512 each) + 2688 pure-Z units in ONE kernel.
// Rationale: r12's separate e/r kernels (1856 blocks each vs ~1024
// resident capacity = 1.8 fill-rounds x2) paid double ramp+tail
// (occupancy 54%).  One 3712-block kernel has a single uniform pure-Z
// tail and one fewer launch boundary.
//   e fused: idx 0..511 -> elems [3538944, 4587520)
//   r fused: idx 0..511 -> elems [4587520, 5636096)
//   units:   u 4096..6783 -> elems [5636096, 8388608)
__global__ __launch_bounds__(512, 6) void k_er_z(
    const ushort* __restrict__ h, const ushort* __restrict__ W2eT,
    const float* __restrict__ b2e, float* __restrict__ e_out,
    const ushort* __restrict__ hr, const ushort* __restrict__ W2rT,
    const float* __restrict__ b2r, float* __restrict__ cr_out,
    ushort* __restrict__ Zd) {
  __shared__ ushort AsL[4096];
  __shared__ ushort BsL[4096];
  const int pos = blockIdx.x;                  // 0..3711
  if (pos >= 1024) {                           // pure-Z: u 4096..6783
    z_unit512(Zd, 4096u + (uint32_t)(pos - 1024));
    return;
  }
  const int idx = pos >> 1;                    // 0..511 per stream
  const int isR = pos & 1;
  const uint32_t j0 = (isR ? 4587520u : 3538944u) + (uint32_t)idx * 2048u +
                      (uint32_t)threadIdx.x * 2u;
  const uint32_t j2 = j0 + 1024u;
  float z0 = 0.0f, z1 = 0.0f, z2 = 0.0f, z3 = 0.0f;
  const int m0 = (idx >> 2) * 128, n0 = (idx & 3) * 128;
  const ushort* A  = isR ? hr   : h;
  const ushort* WT = isR ? W2rT : W2eT;
  const float*  bp = isR ? b2r  : b2e;
  float*        Op = isR ? cr_out : e_out;
  f32x4 acc[4][2] = {};
  gemm_z2_fused<32>(A, WT, m0, n0, Hn, AsL, BsL, acc, j0, j2,
                    z0, z1, z2, z3);
  *(ushort2*)(Zd + j0) = make_ushort2(f2bf(z0), f2bf(z1));
  *(ushort2*)(Zd + j2) = make_ushort2(f2bf(z2), f2bf(z3));
  const int wave = threadIdx.x >> 6, lane = threadIdx.x & 63;
  const int wm = (wave >> 2) << 6, wn = (wave & 3) << 5;
  const int quad = lane >> 4, l15 = lane & 15;
#pragma unroll
  for (int i = 0; i < 4; ++i)
#pragma unroll
    for (int j = 0; j < 2; ++j) {
      const int col = n0 + wn + j * 16 + l15;
      const float bv = bp[col];
#pragma unroll
      for (int r = 0; r < 4; ++r) {
        const int row = m0 + wm + i * 16 + quad * 4 + r;
        Op[(size_t)row * Cn + col] = acc[i][j][r] + bv;
      }
    }
}

// ---------------------------------------------------------------------------
// K4: gate apply (elementwise).  conc = bf16(cr * sigmoid(A32*e - z)).
// Identical f32 arithmetic to the former k_dgemm epilogue.
// ---------------------------------------------------------------------------
__global__ __launch_bounds__(256) void k_gate(
    const float* __restrict__ e, const float* __restrict__ cr,
    ushort* __restrict__ Z) {
  const size_t i = ((size_t)blockIdx.x * 256u + threadIdx.x) * 8u;
  uint4 zv = *(const uint4*)(Z + i);
  ushort zs[8];
  *(uint4*)zs = zv;
  float ee[8], cc[8];
  *(float4*)(ee)     = *(const float4*)(e + i);
  *(float4*)(ee + 4) = *(const float4*)(e + i + 4);
  *(float4*)(cc)     = *(const float4*)(cr + i);
  *(float4*)(cc + 4) = *(const float4*)(cr + i + 4);
  ushort os[8];
#pragma unroll
  for (int k = 0; k < 8; ++k) {
    float z = b2f(zs[k]);
    float g = 1.0f / (1.0f + __expf(z - A32 * ee[k]));
    os[k] = f2bf(cc[k] * g);
  }
  *(uint4*)(Z + i) = *(uint4*)os;
}

// ---------------------------------------------------------------------------
// K5: out = conc @ comps — 128x128 double-buffered core (round-7 verified):
// counted vmcnt + raw s_barrier; sched_barrier(0) after each waitcnt.
// ---------------------------------------------------------------------------
__device__ __forceinline__ void stage4(
    const ushort* ga0, const ushort* ga1,
    const ushort* gb0, const ushort* gb1,
    int k, ushort* As, ushort* Bs, int wo) {
  gload16(ga0 + k, As + wo);
  gload16(ga1 + k, As + 2048 + wo);
  gload16(gb0 + k, Bs + wo);
  gload16(gb1 + k, Bs + 2048 + wo);
}

__device__ __forceinline__ void mfma16(
    const ushort* Ac, const ushort* Bc,
    int wm, int wn, int l15, int rc, f32x4 acc[4][4]) {
  bf16x8 af[4], bfr[4];
#pragma unroll
  for (int i = 0; i < 4; ++i) {
    af[i]  = *(const bf16x8*)&Ac[(wm + i * 16 + l15) * 32 + rc];
    bfr[i] = *(const bf16x8*)&Bc[(wn + i * 16 + l15) * 32 + rc];
  }
#pragma unroll
  for (int i = 0; i < 4; ++i)
#pragma unroll
    for (int j = 0; j < 4; ++j)
      acc[i][j] = __builtin_amdgcn_mfma_f32_16x16x32_bf16(af[i], bfr[j],
                                                          acc[i][j], 0, 0, 0);
}

__global__ __launch_bounds__(256) void k_gemm_out(
    const ushort* __restrict__ A, const ushort* __restrict__ WT,
    float* __restrict__ Out) {
  __shared__ ushort As0[4096];
  __shared__ ushort Bs0[4096];
  __shared__ ushort As1[4096];
  __shared__ ushort Bs1[4096];
  const int t = threadIdx.x;
  const int m0 = blockIdx.y * 128, n0 = blockIdx.x * 128;
  const int wave = t >> 6, lane = t & 63;
  const int row = t >> 2;
  const int col8 = ((t & 3) << 3) ^ (((t >> 3) & 3) << 3);
  const int wm = (wave >> 1) << 6, wn = (wave & 1) << 6;
  const int quad = lane >> 4, l15 = lane & 15;
  const int rc = (quad << 3) ^ (((l15 >> 1) & 3) << 3);
  const int wo = wave * 512;

  const ushort* ga0 = A  + (size_t)(m0 + row) * Cn + col8;
  const ushort* ga1 = A  + (size_t)(m0 + 64 + row) * Cn + col8;
  const ushort* gb0 = WT + (size_t)(n0 + row) * Cn + col8;
  const ushort* gb1 = WT + (size_t)(n0 + 64 + row) * Cn + col8;

  f32x4 acc[4][4] = {};
  stage4(ga0, ga1, gb0, gb1, 0, As0, Bs0, wo);
  for (int k0 = 0; k0 < Cn; k0 += 64) {
    stage4(ga0, ga1, gb0, gb1, k0 + 32, As1, Bs1, wo);
    asm volatile("s_waitcnt vmcnt(4)" ::: "memory");
    __builtin_amdgcn_sched_barrier(0);
    __builtin_amdgcn_s_barrier();
    mfma16(As0, Bs0, wm, wn, l15, rc, acc);
    __builtin_amdgcn_s_barrier();
    if (k0 + 64 < Cn) {
      stage4(ga0, ga1, gb0, gb1, k0 + 64, As0, Bs0, wo);
      asm volatile("s_waitcnt vmcnt(4)" ::: "memory");
    } else {
      asm volatile("s_waitcnt vmcnt(0)" ::: "memory");
    }
    __builtin_amdgcn_sched_barrier(0);
    __builtin_amdgcn_s_barrier();
    mfma16(As1, Bs1, wm, wn, l15, rc, acc);
    __builtin_amdgcn_s_barrier();
  }
#pragma unroll
  for (int i = 0; i < 4; ++i)
#pragma unroll
    for (int j = 0; j < 4; ++j) {
      const int col = n0 + wn + j * 16 + l15;
#pragma unroll
      for (int r = 0; r < 4; ++r) {
        const int row2 = m0 + wm + i * 16 + quad * 4 + r;
        Out[(size_t)row2 * Dn + col] = acc[i][j][r];
      }
    }
}

// ---------------------------------------------------------------------------
extern "C" void kernel_launch(void* const* d_in, const int* in_sizes, int n_in,
                              void* d_out, int out_size, void* d_ws, size_t ws_size,
                              hipStream_t stream) {
  const float* x    = (const float*)d_in[0];
  const float* vc   = (const float*)d_in[1];
  const float* e_sp = (const float*)d_in[2];
  const float* W1e  = (const float*)d_in[3];
  const float* b1e  = (const float*)d_in[4];
  const float* W2e  = (const float*)d_in[5];
  const float* b2e  = (const float*)d_in[6];
  const float* W1r  = (const float*)d_in[7];
  const float* b1r  = (const float*)d_in[8];
  const float* W2r  = (const float*)d_in[9];
  const float* b2r  = (const float*)d_in[10];
  float* out = (float*)d_out;

  // Workspace (88 MiB high-water, unchanged):
  //   4096    W1eT | +1M W2eT | +2M W1rT | +3M W2rT  (bf16 transposed)
  //   +4M     compsT [D][C] bf16
  //   8M      Zdyn [B][C] bf16 (16 MiB): z -> (gate) -> conc in-place
  //   24M     h  [B][H] bf16 (32 MiB); dead after k_er_z -> cr_f32 f32
  //   56M     hr [B][H] bf16 (32 MiB)
  // d_out (32 MiB): x_bf scratch (16 MiB) until k_g13_z; then e_raw f32
  //   (32 MiB) until k_gate; then final out.
  // Z element coverage (complete, disjoint, total 8388608):
  //   prep  zidx 0..2815 x512            = [0,       1441792)
  //   g13   2048 fused x1024             = [1441792, 3538944)
  //   er    512 e-fused x2048            = [3538944, 4587520)
  //   er    512 r-fused x2048            = [4587520, 5636096)
  //   er    2688 units (u 4096..6783)    = [5636096, 8388608)
  char* ws = (char*)d_ws;
  ushort* W1eT   = (ushort*)(ws + (1u << 12));
  ushort* W2eT   = (ushort*)(ws + (1u << 12) + (1u << 20));
  ushort* W1rT   = (ushort*)(ws + (1u << 12) + (2u << 20));
  ushort* W2rT   = (ushort*)(ws + (1u << 12) + (3u << 20));
  ushort* compsT = (ushort*)(ws + (1u << 12) + (4u << 20));
  ushort* Zdyn   = (ushort*)(ws + (8u << 20));
  ushort* h_bf   = (ushort*)(ws + (24u << 20));
  ushort* hr_bf  = (ushort*)(ws + (56u << 20));
  float*  cr_f32 = (float*)(ws + (24u << 20));   // over dead h_bf
  ushort* x_bf   = (ushort*)d_out;               // scratch until k_er_z
  float*  e_f32  = (float*)d_out;                // after k_g13_z

  // 1. prep (cvt_x, 4 transposes, smask) + Z elems [0, 1441792)
  k_prep_z<<<14080, 256, 0, stream>>>(x, x_bf, W1e, W1eT, W2e, W2eT,
                                      W1r, W1rT, W2r, W2rT, vc, e_sp, compsT,
                                      Zdyn);
  // 2. G1+G3: 2048 fused tiles (128x128 + 1024 Z each)
  k_g13_z<<<2048, 512, 0, stream>>>(x_bf, W1eT, b1e, h_bf, W1rT, b1r, hr_bf,
                                    Zdyn);
  // 3. MERGED e_raw + conc_raw + remaining Z (one kernel, 3712 blocks)
  k_er_z<<<3712, 512, 0, stream>>>(h_bf, W2eT, b2e, e_f32,
                                   hr_bf, W2rT, b2r, cr_f32, Zdyn);
  // 4. gate: conc = bf16(cr * sigmoid(A32*e - z)), in-place over Zdyn
  k_gate<<<4096, 256, 0, stream>>>(e_f32, cr_f32, Zdyn);
  // 5. out = conc @ comps
  k_gemm_out<<<dim3(Dn / 128, Bn / 128), 256, 0, stream>>>(Zdyn, compsT, out);
}